// Round 12
// baseline (3573.721 us; speedup 1.0000x reference)
//
#include <hip/hip_runtime.h>
#include <hip/hip_bf16.h>

// ViT forward, MI355X. Round-11 structure + attn_flash upgraded with
// T2 XOR-swizzled K/V/P LDS tiles (conflict-free ds_read_b128) and m204
// XCD-chunked block remap (pair's 5 q-tiles co-located per XCD L2).

typedef unsigned short u16;
typedef __hip_bfloat16 bf16;
typedef __bf16 bf16x8 __attribute__((ext_vector_type(8)));
typedef float f32x4 __attribute__((ext_vector_type(4)));

typedef const __attribute__((address_space(1))) void* gas_ptr;
typedef __attribute__((address_space(3))) void* las_ptr;

#define TOKENS 577
#define TPAD   640
#define DMODEL 512
#define SM_SCALE 0.08838834764831845f   /* 128^-0.5 */
#define LAYER_W 3145728l                /* bf16 elems per layer's weights */

static __device__ __forceinline__ u16 f2b(float v) {
    bf16 t = __float2bfloat16(v);
    return *(u16*)&t;
}

// ---------------------------------------------------------------------------
// Round-3 GEMM (measured best at K=512): 128x128 tile, BK=64.
// OUTMODE 0: plain. 1: patch-embed epilogue (row remap b*577+1+t, +pos).
// ---------------------------------------------------------------------------
template<int OUTMODE, bool GELU>
__global__ __launch_bounds__(256)
void gemm_bt(const u16* __restrict__ A, int lda,
             const u16* __restrict__ Bt, int ldb,
             float* __restrict__ Cf, bf16* __restrict__ Cb, int ldc,
             const float* __restrict__ bias, const float* __restrict__ pos,
             int K, int rows_valid)
{
    __shared__ u16 As[128 * 64];
    __shared__ u16 Bs[128 * 64];
    const int tid  = threadIdx.x;
    const int w    = tid >> 6;
    const int lane = tid & 63;
    const u16* Ab = A + (long)blockIdx.y * 128 * lda;
    const u16* Bb = Bt + (long)blockIdx.x * 128 * ldb;
    const int srow = w * 8 + (lane >> 3);
    const int scol = (lane & 7) * 8;
    const int wr = w >> 1, wc = w & 1;
    const int lr = lane & 15, lg = lane >> 4;
    f32x4 acc[4][4] = {};

    for (int kt = 0; kt < K; kt += 64) {
#pragma unroll
        for (int i = 0; i < 4; ++i) {
            const u16* ag = Ab + (long)(i * 32 + srow) * lda + kt + scol;
            const u16* bg = Bb + (long)(i * 32 + srow) * ldb + kt + scol;
            __builtin_amdgcn_global_load_lds((gas_ptr)ag, (las_ptr)&As[(i * 32 + w * 8) * 64], 16, 0, 0);
            __builtin_amdgcn_global_load_lds((gas_ptr)bg, (las_ptr)&Bs[(i * 32 + w * 8) * 64], 16, 0, 0);
        }
        __syncthreads();
#pragma unroll
        for (int kk = 0; kk < 2; ++kk) {
            const int ko = kk * 32 + lg * 8;
            bf16x8 af[4], bv[4];
#pragma unroll
            for (int m = 0; m < 4; ++m)
                af[m] = *(const bf16x8*)&As[(wr * 64 + m * 16 + lr) * 64 + ko];
#pragma unroll
            for (int n = 0; n < 4; ++n)
                bv[n] = *(const bf16x8*)&Bs[(wc * 64 + n * 16 + lr) * 64 + ko];
#pragma unroll
            for (int m = 0; m < 4; ++m)
#pragma unroll
                for (int n = 0; n < 4; ++n)
                    acc[m][n] = __builtin_amdgcn_mfma_f32_16x16x32_bf16(af[m], bv[n], acc[m][n], 0, 0, 0);
        }
        __syncthreads();
    }

    const int cbase = blockIdx.x * 128 + wc * 64;
    const int rbase = blockIdx.y * 128 + wr * 64;
#pragma unroll
    for (int n = 0; n < 4; ++n) {
        const int c = cbase + n * 16 + lr;
        const float bval = bias ? bias[c] : 0.0f;
#pragma unroll
        for (int m = 0; m < 4; ++m) {
#pragma unroll
            for (int j = 0; j < 4; ++j) {
                const int r = rbase + m * 16 + lg * 4 + j;
                if (r >= rows_valid) continue;
                float v = acc[m][n][j] + bval;
                if constexpr (GELU) v = 0.5f * v * (1.0f + erff(v * 0.70710678118654752f));
                long idx;
                if constexpr (OUTMODE == 1) {
                    const int pb = r / 576, pt = r - pb * 576;
                    v += pos[(long)(1 + pt) * DMODEL + c];
                    idx = (long)(pb * TOKENS + 1 + pt) * ldc + c;
                } else {
                    idx = (long)r * ldc + c;
                }
                if (Cf) Cf[idx] = v;
                if (Cb) Cb[idx] = __float2bfloat16(v);
            }
        }
    }
}

// ---------------------------------------------------------------------------
// BK=32 variant for FFN1 (round-11, kept).
// ---------------------------------------------------------------------------
template<bool GELU>
__global__ __launch_bounds__(256)
void gemm_bt32(const u16* __restrict__ A, int lda,
               const u16* __restrict__ Bt, int ldb,
               bf16* __restrict__ Cb, int ldc,
               const float* __restrict__ bias, int K, int rows_valid)
{
    __shared__ u16 As[128 * 32];
    __shared__ u16 Bs[128 * 32];
    const int tid  = threadIdx.x;
    const int w    = tid >> 6;
    const int lane = tid & 63;
    const u16* Ab = A + (long)blockIdx.y * 128 * lda;
    const u16* Bb = Bt + (long)blockIdx.x * 128 * ldb;
    const int wr = w >> 1, wc = w & 1;
    const int lr = lane & 15, lg = lane >> 4;
    f32x4 acc[4][4] = {};

    for (int kt = 0; kt < K; kt += 32) {
#pragma unroll
        for (int rd = 0; rd < 2; ++rd) {
            const int idx = rd * 256 + tid;
            const int row = idx >> 2, g = idx & 3;
            const int sg = g ^ ((row >> 1) & 3);
            __builtin_amdgcn_global_load_lds(
                (gas_ptr)(Ab + (long)row * lda + kt + sg * 8), (las_ptr)&As[idx * 8], 16, 0, 0);
            __builtin_amdgcn_global_load_lds(
                (gas_ptr)(Bb + (long)row * ldb + kt + sg * 8), (las_ptr)&Bs[idx * 8], 16, 0, 0);
        }
        __syncthreads();
        bf16x8 af[4], bv[4];
#pragma unroll
        for (int m = 0; m < 4; ++m) {
            const int r = wr * 64 + m * 16 + lr;
            af[m] = *(const bf16x8*)&As[r * 32 + (lg ^ ((r >> 1) & 3)) * 8];
        }
#pragma unroll
        for (int n = 0; n < 4; ++n) {
            const int r = wc * 64 + n * 16 + lr;
            bv[n] = *(const bf16x8*)&Bs[r * 32 + (lg ^ ((r >> 1) & 3)) * 8];
        }
#pragma unroll
        for (int m = 0; m < 4; ++m)
#pragma unroll
            for (int n = 0; n < 4; ++n)
                acc[m][n] = __builtin_amdgcn_mfma_f32_16x16x32_bf16(af[m], bv[n], acc[m][n], 0, 0, 0);
        __syncthreads();
    }

    const int cbase = blockIdx.x * 128 + wc * 64;
    const int rbase = blockIdx.y * 128 + wr * 64;
#pragma unroll
    for (int n = 0; n < 4; ++n) {
        const int c = cbase + n * 16 + lr;
        const float bval = bias ? bias[c] : 0.0f;
#pragma unroll
        for (int m = 0; m < 4; ++m) {
#pragma unroll
            for (int j = 0; j < 4; ++j) {
                const int r = rbase + m * 16 + lg * 4 + j;
                if (r >= rows_valid) continue;
                float v = acc[m][n][j] + bval;
                if constexpr (GELU) v = 0.5f * v * (1.0f + erff(v * 0.70710678118654752f));
                Cb[(long)r * ldc + c] = __float2bfloat16(v);
            }
        }
    }
}

// ---------------------------------------------------------------------------
// Fused proj + residual + LayerNorm (round-11, kept).
// ---------------------------------------------------------------------------
__global__ __launch_bounds__(512)
void proj_ln(const u16* __restrict__ A, const u16* __restrict__ Bt,
             const float* __restrict__ res,
             const float* __restrict__ g, const float* __restrict__ b,
             float* __restrict__ outf, bf16* __restrict__ outb, int Mrows)
{
    __shared__ u16 As[64 * 32];
    __shared__ u16 Bs[512 * 32];
    __shared__ float redS[4][64];
    __shared__ float redQ[4][64];
    const int tid = threadIdx.x, wid = tid >> 6, lane = tid & 63;
    const int wm = wid >> 2, wn = wid & 3;
    const int lr = lane & 15, lg = lane >> 4;
    const long row0 = (long)blockIdx.x * 64;
    const u16* Ab = A + row0 * DMODEL;
    f32x4 acc[2][8] = {};

    for (int kt = 0; kt < 512; kt += 32) {
#pragma unroll
        for (int rd = 0; rd < 4; ++rd) {
            const int idx = rd * 512 + tid;
            const int row = idx >> 2, gg = idx & 3;
            const int sg = gg ^ ((row >> 1) & 3);
            __builtin_amdgcn_global_load_lds(
                (gas_ptr)(Bt + (long)row * DMODEL + kt + sg * 8), (las_ptr)&Bs[idx * 8], 16, 0, 0);
        }
        if (tid < 256) {
            const int row = tid >> 2, gg = tid & 3;
            const int sg = gg ^ ((row >> 1) & 3);
            __builtin_amdgcn_global_load_lds(
                (gas_ptr)(Ab + (long)row * DMODEL + kt + sg * 8), (las_ptr)&As[tid * 8], 16, 0, 0);
        }
        __syncthreads();
        bf16x8 af[2], bv[8];
#pragma unroll
        for (int m = 0; m < 2; ++m) {
            const int r = wm * 32 + m * 16 + lr;
            af[m] = *(const bf16x8*)&As[r * 32 + (lg ^ ((r >> 1) & 3)) * 8];
        }
#pragma unroll
        for (int n = 0; n < 8; ++n) {
            const int r = wn * 128 + n * 16 + lr;
            bv[n] = *(const bf16x8*)&Bs[r * 32 + (lg ^ ((r >> 1) & 3)) * 8];
        }
#pragma unroll
        for (int m = 0; m < 2; ++m)
#pragma unroll
            for (int n = 0; n < 8; ++n)
                acc[m][n] = __builtin_amdgcn_mfma_f32_16x16x32_bf16(af[m], bv[n], acc[m][n], 0, 0, 0);
        __syncthreads();
    }

    float ps[2][4], pq[2][4];
#pragma unroll
    for (int m = 0; m < 2; ++m)
#pragma unroll
        for (int j = 0; j < 4; ++j) {
            const long r = row0 + wm * 32 + m * 16 + lg * 4 + j;
            const bool valid = r < Mrows;
            float s = 0.f, q = 0.f;
#pragma unroll
            for (int n = 0; n < 8; ++n) {
                float t = acc[m][n][j];
                if (valid) t += res[r * DMODEL + wn * 128 + n * 16 + lr];
                acc[m][n][j] = t;
                s += t; q += t * t;
            }
            ps[m][j] = s; pq[m][j] = q;
        }
#pragma unroll
    for (int o = 1; o < 16; o <<= 1)
#pragma unroll
        for (int m = 0; m < 2; ++m)
#pragma unroll
            for (int j = 0; j < 4; ++j) {
                ps[m][j] += __shfl_xor(ps[m][j], o);
                pq[m][j] += __shfl_xor(pq[m][j], o);
            }
    if (lr == 0) {
#pragma unroll
        for (int m = 0; m < 2; ++m)
#pragma unroll
            for (int j = 0; j < 4; ++j) {
                const int ri = wm * 32 + m * 16 + lg * 4 + j;
                redS[wn][ri] = ps[m][j];
                redQ[wn][ri] = pq[m][j];
            }
    }
    __syncthreads();
    if (tid < 64) {
        const float s = redS[0][tid] + redS[1][tid] + redS[2][tid] + redS[3][tid];
        const float q = redQ[0][tid] + redQ[1][tid] + redQ[2][tid] + redQ[3][tid];
        const float mean = s * (1.f / 512.f);
        const float var = q * (1.f / 512.f) - mean * mean;
        redS[0][tid] = mean;
        redQ[0][tid] = rsqrtf(var + 1e-5f);
    }
    __syncthreads();
#pragma unroll
    for (int m = 0; m < 2; ++m)
#pragma unroll
        for (int j = 0; j < 4; ++j) {
            const int ri = wm * 32 + m * 16 + lg * 4 + j;
            const long r = row0 + ri;
            if (r >= Mrows) continue;
            const float mean = redS[0][ri], rs = redQ[0][ri];
#pragma unroll
            for (int n = 0; n < 8; ++n) {
                const int c = wn * 128 + n * 16 + lr;
                const float o = (acc[m][n][j] - mean) * rs * g[c] + b[c];
                outf[r * DMODEL + c] = o;
                outb[r * DMODEL + c] = __float2bfloat16(o);
            }
        }
}

// ---------------------------------------------------------------------------
// 8-phase GEMM (round-8, refcheck'd). Used for FFN2 (K=2048).
// ---------------------------------------------------------------------------
template<int OUTMODE, bool GELU>
__global__ __launch_bounds__(512, 1)
void gemm8(const u16* __restrict__ A, int lda,
           const u16* __restrict__ Bt, int ldb,
           float* __restrict__ Cf, bf16* __restrict__ Cb, int ldc,
           const float* __restrict__ bias, const float* __restrict__ pos,
           int K, int rows_valid)
{
    __shared__ u16 Ash[2][2][256 * 32];
    __shared__ u16 Bsh[2][2][256 * 32];
    const int tid = threadIdx.x, wid = tid >> 6, lane = tid & 63;
    const int wm = wid >> 2, wn = wid & 3;
    const int lr = lane & 15, lg = lane >> 4;
    const u16* Ab = A + (long)blockIdx.y * 256 * lda;
    const u16* Bb = Bt + (long)blockIdx.x * 256 * ldb;
    const int srow = tid >> 2;
    const int soct = ((tid & 3) ^ (srow & 3)) * 8;
    const int slot8 = (lg ^ (lr & 3)) * 8;

    f32x4 acc[8][4] = {};

    auto stage = [&](u16* dst, const u16* src, int ld, int kt, int kh) {
#pragma unroll
        for (int i = 0; i < 2; ++i)
            __builtin_amdgcn_global_load_lds(
                (gas_ptr)(src + (long)(i * 128 + srow) * ld + kt * 64 + kh * 32 + soct),
                (las_ptr)(dst + (i * 512 + tid) * 8), 16, 0, 0);
    };

#define VMW(n) { asm volatile("s_waitcnt vmcnt(" #n ")" ::: "memory"); \
                 __builtin_amdgcn_sched_barrier(0); }
#define MFMA16(A0)                                                              \
    __builtin_amdgcn_s_setprio(1);                                             \
    _Pragma("unroll")                                                           \
    for (int m = 0; m < 4; ++m)                                                 \
        _Pragma("unroll")                                                       \
        for (int n = 0; n < 4; ++n)                                             \
            acc[(A0) + m][n] = __builtin_amdgcn_mfma_f32_16x16x32_bf16(         \
                af[m], bfr[n], acc[(A0) + m][n], 0, 0, 0);                      \
    __builtin_amdgcn_s_setprio(0);

    const int nt = K / 64;
    stage(&Ash[0][0][0], Ab, lda, 0, 0);
    stage(&Bsh[0][0][0], Bb, ldb, 0, 0);
    stage(&Ash[0][1][0], Ab, lda, 0, 1);
    stage(&Bsh[0][1][0], Bb, ldb, 0, 1);
    VMW(4);
    __builtin_amdgcn_s_barrier();

    for (int t = 0; t < nt; ++t) {
        const int db = t & 1;
        const bool nx = (t + 1 < nt);
        bf16x8 af[4], bfr[4];

#pragma unroll
        for (int n = 0; n < 4; ++n)
            bfr[n] = *(const bf16x8*)&Bsh[db][0][(wn * 64 + n * 16 + lr) * 32 + slot8];
#pragma unroll
        for (int m = 0; m < 4; ++m)
            af[m] = *(const bf16x8*)&Ash[db][0][(wm * 128 + m * 16 + lr) * 32 + slot8];
        if (nx) stage(&Ash[db ^ 1][0][0], Ab, lda, t + 1, 0);
        __builtin_amdgcn_s_barrier();
        MFMA16(0)
        __builtin_amdgcn_s_barrier();

#pragma unroll
        for (int m = 0; m < 4; ++m)
            af[m] = *(const bf16x8*)&Ash[db][0][(wm * 128 + 64 + m * 16 + lr) * 32 + slot8];
        if (nx) { stage(&Bsh[db ^ 1][0][0], Bb, ldb, t + 1, 0); VMW(4); }
        else    { VMW(0); }
        __builtin_amdgcn_s_barrier();
        MFMA16(4)
        __builtin_amdgcn_s_barrier();

#pragma unroll
        for (int n = 0; n < 4; ++n)
            bfr[n] = *(const bf16x8*)&Bsh[db][1][(wn * 64 + n * 16 + lr) * 32 + slot8];
#pragma unroll
        for (int m = 0; m < 4; ++m)
            af[m] = *(const bf16x8*)&Ash[db][1][(wm * 128 + m * 16 + lr) * 32 + slot8];
        if (nx) stage(&Ash[db ^ 1][1][0], Ab, lda, t + 1, 1);
        __builtin_amdgcn_s_barrier();
        MFMA16(0)
        __builtin_amdgcn_s_barrier();

#pragma unroll
        for (int m = 0; m < 4; ++m)
            af[m] = *(const bf16x8*)&Ash[db][1][(wm * 128 + 64 + m * 16 + lr) * 32 + slot8];
        if (nx) { stage(&Bsh[db ^ 1][1][0], Bb, ldb, t + 1, 1); VMW(4); }
        __builtin_amdgcn_s_barrier();
        MFMA16(4)
        __builtin_amdgcn_s_barrier();
    }
#undef MFMA16
#undef VMW

    const int cbase = blockIdx.x * 256 + wn * 64;
    const int rbase = blockIdx.y * 256 + wm * 128;
#pragma unroll
    for (int n = 0; n < 4; ++n) {
        const int c = cbase + n * 16 + lr;
        const float bval = bias ? bias[c] : 0.0f;
#pragma unroll
        for (int a = 0; a < 8; ++a) {
#pragma unroll
            for (int j = 0; j < 4; ++j) {
                const int r = rbase + a * 16 + lg * 4 + j;
                if (r >= rows_valid) continue;
                float v = acc[a][n][j] + bval;
                if constexpr (GELU) v = 0.5f * v * (1.0f + erff(v * 0.70710678118654752f));
                long idx;
                if constexpr (OUTMODE == 1) {
                    const int pb = r / 576, pt = r - pb * 576;
                    v += pos[(long)(1 + pt) * DMODEL + c];
                    idx = (long)(pb * TOKENS + 1 + pt) * ldc + c;
                } else {
                    idx = (long)r * ldc + c;
                }
                if (Cf) Cf[idx] = v;
                if (Cb) Cb[idx] = __float2bfloat16(v);
            }
        }
    }
}

// ---------------------------------------------------------------------------
// Fused flash attention, v2: XOR-swizzled K/V/P LDS (octet ^= row&7; staged
// via pre-swizzled GLOBAL source, linear LDS dst) + m204 XCD-chunked remap
// (all 5 q-tiles of a pair on one XCD -> K/V L2-resident).
// Grid: 1D, 5*NP blocks. qkv layout: [row][kk*512 + h*128 + d].
// ---------------------------------------------------------------------------
__global__ __launch_bounds__(256, 2)
void attn_flash(const u16* __restrict__ qkv, const u16* __restrict__ vhT,
                bf16* __restrict__ ob)
{
    __shared__ u16 ldsA[128 * 128];   // K tile, then P tile (swizzled)
    __shared__ u16 ldsB[128 * 128];   // V^T tile [d][kv]    (swizzled)
    const int nwg = gridDim.x;
    const int orig = blockIdx.x;
    const int q8 = nwg >> 3, r8 = nwg & 7;
    const int xcd = orig & 7, j0 = orig >> 3;
    const int nid = (xcd < r8 ? xcd * (q8 + 1) : r8 * (q8 + 1) + (xcd - r8) * q8) + j0;
    const int pair = nid / 5;
    const int q0 = (nid % 5) * 128;

    const int tid = threadIdx.x;
    const int w = tid >> 6, lane = tid & 63;
    const int lr = lane & 15, lg = lane >> 4;
    const int b = pair >> 2, h = pair & 3;
    const long rowbase = (long)b * TOKENS;
    const int swst = (w * 4 + lg) & 7;            // staging row & 7 (p-invariant)
    const int swrd = lr & 7;                      // read row & 7 (16-mult drops)

    bf16x8 qf[2][4];
#pragma unroll
    for (int m = 0; m < 2; ++m)
#pragma unroll
        for (int kf = 0; kf < 4; ++kf) {
            const long r = rowbase + q0 + w * 32 + m * 16 + lr;
            qf[m][kf] = *(const bf16x8*)&qkv[r * 1536 + h * 128 + kf * 32 + lg * 8];
        }

    float mrun[2][4], lrun[2][4];
#pragma unroll
    for (int m = 0; m < 2; ++m)
#pragma unroll
        for (int j = 0; j < 4; ++j) { mrun[m][j] = -1e30f; lrun[m][j] = 0.f; }
    f32x4 oacc[2][8] = {};

    for (int kv0 = 0; kv0 < TPAD; kv0 += 128) {
        // stage K [kv][d] and V^T [d][kv]; LDS dst linear, global src octet
        // pre-swizzled: slot s of row r holds global octet s ^ (r&7).
        {
            const u16* kg = qkv + (rowbase + kv0) * 1536 + 512 + h * 128;
            const u16* vg = vhT + ((long)pair * 128) * TPAD + kv0;
            const int soff = (lr ^ swst) * 8;
#pragma unroll
            for (int p = 0; p < 8; ++p) {
                const int i = p * 16 + w * 4 + lg;
                __builtin_amdgcn_global_load_lds((gas_ptr)(kg + (long)i * 1536 + soff),
                                                 (las_ptr)&ldsA[(p * 16 + w * 4) * 128], 16, 0, 0);
                __builtin_amdgcn_global_load_lds((gas_ptr)(vg + (long)i * TPAD + soff),
                                                 (las_ptr)&ldsB[(p * 16 + w * 4) * 128], 16, 0, 0);
            }
        }
        __syncthreads();

        // S = Q K^T  (K rows n*16+lr -> octet (kf*4+lg)^(lr&7))
        f32x4 s[2][8] = {};
#pragma unroll
        for (int kf = 0; kf < 4; ++kf) {
            const int oct = ((kf * 4 + lg) ^ swrd) * 8;
            bf16x8 bv[8];
#pragma unroll
            for (int n = 0; n < 8; ++n)
                bv[n] = *(const bf16x8*)&ldsA[(n * 16 + lr) * 128 + oct];
            __builtin_amdgcn_s_setprio(1);
#pragma unroll
            for (int m = 0; m < 2; ++m)
#pragma unroll
                for (int n = 0; n < 8; ++n)
                    s[m][n] = __builtin_amdgcn_mfma_f32_16x16x32_bf16(qf[m][kf], bv[n], s[m][n], 0, 0, 0);
            __builtin_amdgcn_s_setprio(0);
        }

        float sc[2][4];
#pragma unroll
        for (int m = 0; m < 2; ++m)
#pragma unroll
            for (int jj = 0; jj < 4; ++jj) {
                float mx = mrun[m][jj];
#pragma unroll
                for (int n = 0; n < 8; ++n) {
                    const int col = kv0 + n * 16 + lr;
                    float v = s[m][n][jj] * SM_SCALE;
                    v = (col < TOKENS) ? v : -1e30f;
                    s[m][n][jj] = v;
                    mx = fmaxf(mx, v);
                }
#pragma unroll
                for (int o = 1; o < 16; o <<= 1) mx = fmaxf(mx, __shfl_xor(mx, o));
                const float f = __expf(mrun[m][jj] - mx);
                sc[m][jj] = f;
                float sum = 0.f;
#pragma unroll
                for (int n = 0; n < 8; ++n) {
                    const float p = __expf(s[m][n][jj] - mx);
                    s[m][n][jj] = p;
                    sum += p;
                }
#pragma unroll
                for (int o = 1; o < 16; o <<= 1) sum += __shfl_xor(sum, o);
                lrun[m][jj] = lrun[m][jj] * f + sum;
                mrun[m][jj] = mx;
            }
#pragma unroll
        for (int m = 0; m < 2; ++m)
#pragma unroll
            for (int n = 0; n < 8; ++n)
#pragma unroll
                for (int jj = 0; jj < 4; ++jj) oacc[m][n][jj] *= sc[m][jj];

        __syncthreads();
        // write P (swizzled): elem col c of row r -> slot ((c>>3)^(r&7))*8 + (c&7)
#pragma unroll
        for (int m = 0; m < 2; ++m)
#pragma unroll
            for (int jj = 0; jj < 4; ++jj) {
                const int prow = w * 32 + m * 16 + lg * 4 + jj;
                const int p7 = prow & 7;
#pragma unroll
                for (int n = 0; n < 8; ++n) {
                    const int c = n * 16 + lr;
                    ldsA[prow * 128 + (((c >> 3) ^ p7) << 3) + (c & 7)] = f2b(s[m][n][jj]);
                }
            }
        __syncthreads();

        // O += P V  (P rows w*32+m*16+lr, V rows n*16+lr; octet ^(lr&7))
#pragma unroll
        for (int kf = 0; kf < 4; ++kf) {
            const int oct = ((kf * 4 + lg) ^ swrd) * 8;
            bf16x8 pa[2];
#pragma unroll
            for (int m = 0; m < 2; ++m)
                pa[m] = *(const bf16x8*)&ldsA[(w * 32 + m * 16 + lr) * 128 + oct];
            __builtin_amdgcn_s_setprio(1);
#pragma unroll
            for (int n = 0; n < 8; ++n) {
                const bf16x8 vb = *(const bf16x8*)&ldsB[(n * 16 + lr) * 128 + oct];
#pragma unroll
                for (int m = 0; m < 2; ++m)
                    oacc[m][n] = __builtin_amdgcn_mfma_f32_16x16x32_bf16(pa[m], vb, oacc[m][n], 0, 0, 0);
            }
            __builtin_amdgcn_s_setprio(0);
        }
        __syncthreads();
    }

#pragma unroll
    for (int m = 0; m < 2; ++m)
#pragma unroll
        for (int jj = 0; jj < 4; ++jj) {
            const float inv = 1.f / lrun[m][jj];
            const int q = q0 + w * 32 + m * 16 + lg * 4 + jj;
            if (q >= TOKENS) continue;
#pragma unroll
            for (int n = 0; n < 8; ++n)
                ob[(rowbase + q) * DMODEL + h * 128 + n * 16 + lr] =
                    __float2bfloat16(oacc[m][n][jj] * inv);
        }
}

// ---------------------------------------------------------------------------
// Patch-embed weight transpose (once).
// ---------------------------------------------------------------------------
__global__ __launch_bounds__(256)
void wtrans(const float* __restrict__ W, bf16* __restrict__ WT, int K, int N)
{
    __shared__ float tile[32][33];
    const int n0 = blockIdx.x * 32, k0 = blockIdx.y * 32;
    const int tx = threadIdx.x & 31, ty = threadIdx.x >> 5;
#pragma unroll
    for (int i = 0; i < 4; ++i)
        tile[ty + i * 8][tx] = W[(long)(k0 + ty + i * 8) * N + n0 + tx];
    __syncthreads();
#pragma unroll
    for (int i = 0; i < 4; ++i)
        WT[(long)(n0 + ty + i * 8) * K + k0 + tx] = __float2bfloat16(tile[tx][ty + i * 8]);
}

// ---------------------------------------------------------------------------
// Layer weight transpose (round-11, kept).
// ---------------------------------------------------------------------------
__global__ __launch_bounds__(256)
void wtrans_layers(const float* __restrict__ Wqkv, const float* __restrict__ W0,
                   const float* __restrict__ W1, const float* __restrict__ W2,
                   bf16* __restrict__ out, int layer0)
{
    const int bb = blockIdx.x;
    const int sl = bb / 3072;
    const int l = layer0 + sl;
    int t = bb % 3072;
    bf16* base = out + (long)sl * LAYER_W;
    const float* W; bf16* WT; int K, N; bool perm = false;
    if (t < 768)       {            W = Wqkv + (long)l * 512 * 1536; WT = base;           K = 512;  N = 1536; perm = true; }
    else if (t < 1024) { t -= 768;  W = W0   + (long)l * 512 * 512;  WT = base + 786432;  K = 512;  N = 512;  }
    else if (t < 2048) { t -= 1024; W = W1   + (long)l * 512 * 2048; WT = base + 1048576; K = 512;  N = 2048; }
    else               { t -= 2048; W = W2   + (long)l * 2048 * 512; WT = base + 2097152; K = 2048; N = 512;  }
    const int nx = N / 32;
    const int n0 = (t % nx) * 32, k0 = (t / nx) * 32;
    __shared__ float tile[32][33];
    const int tx = threadIdx.x & 31, ty = threadIdx.x >> 5;
#pragma unroll
    for (int i = 0; i < 4; ++i)
        tile[ty + i * 8][tx] = W[(long)(k0 + ty + i * 8) * N + n0 + tx];
    __syncthreads();
#pragma unroll
    for (int i = 0; i < 4; ++i) {
        int n = n0 + ty + i * 8;
        if (perm) {
            const int d = n / 12, rr = n % 12;
            n = (rr >> 2) * 512 + (rr & 3) * 128 + d;
        }
        WT[(long)n * K + k0 + tx] = __float2bfloat16(tile[tx][ty + i * 8]);
    }
}

// ---------------------------------------------------------------------------
__global__ __launch_bounds__(64)
void patch_gather(const float* __restrict__ img, bf16* __restrict__ pat)
{
    const int bid = blockIdx.x;
    const int x  = bid % 24;
    const int p1 = (bid / 24) % 16;
    const int b  = bid / (24 * 16);
    __shared__ bf16 lds[24][48];
    const int lane = threadIdx.x;
    const int h = p1 * 24 + x;
    for (int c = 0; c < 3; ++c) {
        const float* row = img + ((long)(b * 3 + c) * 384 + h) * 384;
#pragma unroll
        for (int i = 0; i < 6; ++i) {
            const int wpix = lane + i * 64;
            const float v = row[wpix];
            const int y = wpix % 24, p2 = wpix / 24;
            lds[y][p2 * 3 + c] = __float2bfloat16(v);
        }
    }
    __syncthreads();
    for (int idx = lane; idx < 24 * 48; idx += 64) {
        const int y = idx / 48, j = idx % 48;
        pat[(long)(b * 576 + x * 24 + y) * 768 + p1 * 48 + j] = lds[y][j];
    }
}

__global__ __launch_bounds__(256)
void clsfill(const float* __restrict__ cls, const float* __restrict__ pos,
             float* __restrict__ tokf, bf16* __restrict__ xb)
{
    const int i = blockIdx.x * 256 + threadIdx.x;
    const int b = i >> 9, d = i & 511;
    const float v = cls[d] + pos[d];
    tokf[(long)b * TOKENS * DMODEL + d] = v;
    xb[(long)b * TOKENS * DMODEL + d] = __float2bfloat16(v);
}

__global__ __launch_bounds__(256)
void repack_v(const u16* __restrict__ qkv, u16* __restrict__ vhT)
{
    __shared__ u16 lds[64][136];
    const int bid = blockIdx.x;
    const int tt = bid % 10, pair = bid / 10;
    const int b = pair >> 2, h = pair & 3;
    const int tid = threadIdx.x;
    const int tl = tid >> 2, seg = tid & 3;
    const long row = (long)b * TOKENS + tt * 64 + tl;
    const u16* src = qkv + row * 1536 + 1024 + h * 128 + seg * 32;
#pragma unroll
    for (int u = 0; u < 4; ++u)
        *(uint4*)&lds[tl][seg * 32 + u * 8] = *(const uint4*)&src[u * 8];
    __syncthreads();
    const int d = tid >> 1, th = (tid & 1) * 32;
    u16* dst = vhT + ((long)pair * 128 + d) * TPAD + tt * 64 + th;
#pragma unroll
    for (int blk = 0; blk < 4; ++blk) {
        uint4 pk; u16* pp = (u16*)&pk;
#pragma unroll
        for (int j = 0; j < 8; ++j) {
            const int t = tt * 64 + th + blk * 8 + j;
            pp[j] = (t < TOKENS) ? lds[th + blk * 8 + j][d] : (u16)0;
        }
        *(uint4*)&dst[blk * 8] = pk;
    }
}

// y = LN(xin + res)*g + b  (LN2)
__global__ __launch_bounds__(256)
void resln(const float* __restrict__ xin, const float* __restrict__ res,
           const float* __restrict__ g, const float* __restrict__ b,
           float* __restrict__ outf, bf16* __restrict__ outb, int nrows)
{
    const int row = blockIdx.x * 4 + (threadIdx.x >> 6);
    if (row >= nrows) return;
    const int lane = threadIdx.x & 63;
    const float* p1 = xin + (long)row * DMODEL;
    const float* p2 = res + (long)row * DMODEL;
    float v[8];
    float s = 0.f;
#pragma unroll
    for (int i = 0; i < 8; ++i) { v[i] = p1[lane + i * 64] + p2[lane + i * 64]; s += v[i]; }
#pragma unroll
    for (int o = 32; o; o >>= 1) s += __shfl_xor(s, o);
    const float mean = s * (1.f / 512.f);
    float q = 0.f;
#pragma unroll
    for (int i = 0; i < 8; ++i) { const float d = v[i] - mean; q += d * d; }
#pragma unroll
    for (int o = 32; o; o >>= 1) q += __shfl_xor(q, o);
    const float rs = rsqrtf(q * (1.f / 512.f) + 1e-5f);
#pragma unroll
    for (int i = 0; i < 8; ++i) {
        const int c = lane + i * 64;
        const float o = (v[i] - mean) * rs * g[c] + b[c];
        outf[(long)row * DMODEL + c] = o;
        outb[(long)row * DMODEL + c] = __float2bfloat16(o);
    }
}

__global__ __launch_bounds__(64)
void head_k(const float* __restrict__ tokf, const float* __restrict__ Wh,
            const float* __restrict__ bh, float* __restrict__ out)
{
    const int b = blockIdx.x;
    const int lane = threadIdx.x;
    const float* x = tokf + (long)b * TOKENS * DMODEL;
    float acc[10] = {};
#pragma unroll
    for (int i = 0; i < 8; ++i) {
        const int d = lane + i * 64;
        const float xv = x[d];
        const float* wr = Wh + (long)d * 10;
#pragma unroll
        for (int c = 0; c < 10; ++c) acc[c] += xv * wr[c];
    }
#pragma unroll
    for (int c = 0; c < 10; ++c)
#pragma unroll
        for (int o = 32; o; o >>= 1) acc[c] += __shfl_xor(acc[c], o);
    if (lane == 0) {
#pragma unroll
        for (int c = 0; c < 10; ++c) out[b * 10 + c] = acc[c] + bh[c];
    }
}

// ---------------------------------------------------------------------------
extern "C" void kernel_launch(void* const* d_in, const int* in_sizes, int n_in,
                              void* d_out, int out_size, void* d_ws, size_t ws_size,
                              hipStream_t stream)
{
    (void)in_sizes; (void)n_in; (void)out_size;
    const float* img    = (const float*)d_in[0];
    const float* Wpatch = (const float*)d_in[1];
    const float* bpatch = (const float*)d_in[2];
    const float* clstk  = (const float*)d_in[3];
    const float* pos    = (const float*)d_in[4];
    const float* Wqkv   = (const float*)d_in[5];
    const float* W0     = (const float*)d_in[6];
    const float* g1     = (const float*)d_in[7];
    const float* b1     = (const float*)d_in[8];
    const float* g2     = (const float*)d_in[9];
    const float* b2     = (const float*)d_in[10];
    const float* W1     = (const float*)d_in[11];
    const float* bb1    = (const float*)d_in[12];
    const float* W2     = (const float*)d_in[13];
    const float* bb2    = (const float*)d_in[14];
    const float* Whead  = (const float*)d_in[15];
    const float* bhead  = (const float*)d_in[16];

    // ---- config ladder: (batch chunk, weight buffers) ----
    static const int cand[7][2] = {{32,6},{32,1},{16,1},{8,1},{4,1},{2,1},{1,1}};
    int Bc = 0, nW = 1;
    size_t o_tokf=0, o_xb=0, o_R1=0, o_R2=0, o_ob=0, o_wp=0, o_wr=0;
    for (int ci = 0; ci < 7; ++ci) {
        const int bc = cand[ci][0], nw = cand[ci][1];
        const long Mrows = (long)bc * TOKENS;
        const long Mpad  = ((Mrows + 255) / 256) * 256;
        size_t off = 0;
        auto take = [&](size_t sz) { size_t o = off; off += (sz + 255) & ~(size_t)255; return o; };
        size_t t_tokf = take((size_t)Mpad * 512 * 4);
        size_t t_xb   = take((size_t)Mpad * 512 * 2);
        size_t t_R1   = take((size_t)Mpad * 2048 * 2);          // pat | qkv | h1b
        size_t r2a = (size_t)bc * 4 * TPAD * 128 * 2;           // vhT
        size_t r2b = (size_t)Mpad * 512 * 4;                    // t1 (f32)
        size_t t_R2 = take(r2a > r2b ? r2a : r2b);
        size_t t_ob   = take((size_t)Mpad * 512 * 2);
        size_t t_wp   = take((size_t)512 * 768 * 2);
        size_t t_wr   = take((size_t)nw * LAYER_W * 2);
        if (off <= ws_size) {
            Bc = bc; nW = nw;
            o_tokf=t_tokf; o_xb=t_xb; o_R1=t_R1; o_R2=t_R2; o_ob=t_ob; o_wp=t_wp; o_wr=t_wr;
            break;
        }
    }
    if (Bc == 0) return;

    const long Mrows = (long)Bc * TOKENS;
    const long Mpad  = ((Mrows + 255) / 256) * 256;
    const int  NP    = Bc * 4;
    const int  gy128 = (int)(Mpad / 128);
    const int  gy256 = (int)(Mpad / 256);
    const int  nproj = (int)((Mrows + 63) / 64);
    const long patRows = ((long)Bc * 576 + 127) / 128 * 128;

    char* base = (char*)d_ws;
    float* tokf = (float*)(base + o_tokf);
    bf16*  xb   = (bf16*)(base + o_xb);
    char*  R1   = base + o_R1;
    char*  R2   = base + o_R2;
    bf16*  ob   = (bf16*)(base + o_ob);
    bf16*  wpT  = (bf16*)(base + o_wp);
    bf16*  wAll = (bf16*)(base + o_wr);

    u16*  qkvb = (u16*)R1;
    bf16* pat  = (bf16*)R1;
    u16*  h1b  = (u16*)R1;
    u16*  vhT  = (u16*)R2;
    float* t1  = (float*)R2;

    wtrans<<<dim3(512 / 32, 768 / 32), 256, 0, stream>>>(Wpatch, wpT, 768, 512);
    if (nW == 6)
        wtrans_layers<<<6 * 3072, 256, 0, stream>>>(Wqkv, W0, W1, W2, wAll, 0);

    const int nchunks = 32 / Bc;
    for (int ch = 0; ch < nchunks; ++ch) {
        const float* img_c = img + (long)ch * Bc * 3 * 384 * 384;

        hipMemsetAsync(xb, 0, (size_t)Mpad * 512 * 2, stream);   // pad rows -> exact 0
        clsfill<<<Bc * 2, 256, 0, stream>>>(clstk, pos, tokf, xb);
        patch_gather<<<Bc * 16 * 24, 64, 0, stream>>>(img_c, pat);
        gemm_bt<1, false><<<dim3(4, (int)(patRows / 128)), 256, 0, stream>>>(
            (const u16*)pat, 768, (const u16*)wpT, 768,
            tokf, xb, 512, bpatch, pos, 768, Bc * 576);

        for (int l = 0; l < 6; ++l) {
            const bf16* wL = wAll + (nW == 6 ? (long)l * LAYER_W : 0);
            if (nW == 1)
                wtrans_layers<<<3072, 256, 0, stream>>>(Wqkv, W0, W1, W2, wAll, l);
            const u16* wqkvT = (const u16*)wL;
            const u16* w0T   = (const u16*)(wL + 786432);
            const u16* w1T   = (const u16*)(wL + 1048576);
            const u16* w2T   = (const u16*)(wL + 2097152);

            // qkv = x @ Wqkv  (permuted cols: kk*512 + h*128 + d)
            gemm_bt<0, false><<<dim3(12, gy128), 256, 0, stream>>>(
                (const u16*)xb, 512, wqkvT, 512,
                nullptr, (bf16*)qkvb, 1536, nullptr, nullptr, 512, (int)Mpad);

            repack_v<<<NP * 10, 256, 0, stream>>>(qkvb, vhT);
            attn_flash<<<5 * NP, 256, 0, stream>>>(qkvb, vhT, ob);

            // fused proj + residual + LN1 -> tokf, xb
            proj_ln<<<nproj, 512, 0, stream>>>(
                (const u16*)ob, w0T, tokf, g1 + l * 512, b1 + l * 512,
                tokf, xb, (int)Mrows);

            // h1 = gelu(y @ W1 + bb1)
            gemm_bt32<true><<<dim3(16, gy128), 256, 0, stream>>>(
                (const u16*)xb, 512, w1T, 512,
                (bf16*)h1b, 2048, bb1 + l * 2048, 512, (int)Mrows);

            // t1 = h1 @ W2 + bb2  (K=2048 -> 8-phase pipeline)
            gemm8<0, false><<<dim3(2, gy256), 512, 0, stream>>>(
                (const u16*)h1b, 2048, w2T, 2048,
                t1, nullptr, 512, bb2 + l * 512, nullptr, 2048, (int)Mrows);
            // x = LN(t1 + y) -> tokf, xb
            resln<<<(int)((Mrows + 3) / 4), 256, 0, stream>>>(
                t1, tokf, g2 + l * 512, b2 + l * 512, tokf, xb, (int)Mrows);
        }

        head_k<<<Bc, 64, 0, stream>>>(tokf, Whead, bhead, (float*)d_out + (long)ch * Bc * 10);
    }
}

// Round 13
// 2831.969 us; speedup vs baseline: 1.2619x; 1.2619x over previous
//
#include <hip/hip_runtime.h>
#include <hip/hip_bf16.h>

// ViT forward, MI355X. Round-11 structure; attn_flash v3: kv-tile=64, K/V
// double-buffered with counted-vmcnt 2-deep pipeline (stage t+1 hidden under
// tile t compute), wave-private P buffer (no mid-tile barriers), XOR-swizzled
// K/V/P LDS. No XCD remap (round-12 regression reverted).

typedef unsigned short u16;
typedef __hip_bfloat16 bf16;
typedef __bf16 bf16x8 __attribute__((ext_vector_type(8)));
typedef float f32x4 __attribute__((ext_vector_type(4)));

typedef const __attribute__((address_space(1))) void* gas_ptr;
typedef __attribute__((address_space(3))) void* las_ptr;

#define TOKENS 577
#define TPAD   640
#define DMODEL 512
#define SM_SCALE 0.08838834764831845f   /* 128^-0.5 */
#define LAYER_W 3145728l                /* bf16 elems per layer's weights */

static __device__ __forceinline__ u16 f2b(float v) {
    bf16 t = __float2bfloat16(v);
    return *(u16*)&t;
}

// ---------------------------------------------------------------------------
// Round-3 GEMM (measured best at K=512): 128x128 tile, BK=64.
// OUTMODE 0: plain. 1: patch-embed epilogue (row remap b*577+1+t, +pos).
// ---------------------------------------------------------------------------
template<int OUTMODE, bool GELU>
__global__ __launch_bounds__(256)
void gemm_bt(const u16* __restrict__ A, int lda,
             const u16* __restrict__ Bt, int ldb,
             float* __restrict__ Cf, bf16* __restrict__ Cb, int ldc,
             const float* __restrict__ bias, const float* __restrict__ pos,
             int K, int rows_valid)
{
    __shared__ u16 As[128 * 64];
    __shared__ u16 Bs[128 * 64];
    const int tid  = threadIdx.x;
    const int w    = tid >> 6;
    const int lane = tid & 63;
    const u16* Ab = A + (long)blockIdx.y * 128 * lda;
    const u16* Bb = Bt + (long)blockIdx.x * 128 * ldb;
    const int srow = w * 8 + (lane >> 3);
    const int scol = (lane & 7) * 8;
    const int wr = w >> 1, wc = w & 1;
    const int lr = lane & 15, lg = lane >> 4;
    f32x4 acc[4][4] = {};

    for (int kt = 0; kt < K; kt += 64) {
#pragma unroll
        for (int i = 0; i < 4; ++i) {
            const u16* ag = Ab + (long)(i * 32 + srow) * lda + kt + scol;
            const u16* bg = Bb + (long)(i * 32 + srow) * ldb + kt + scol;
            __builtin_amdgcn_global_load_lds((gas_ptr)ag, (las_ptr)&As[(i * 32 + w * 8) * 64], 16, 0, 0);
            __builtin_amdgcn_global_load_lds((gas_ptr)bg, (las_ptr)&Bs[(i * 32 + w * 8) * 64], 16, 0, 0);
        }
        __syncthreads();
#pragma unroll
        for (int kk = 0; kk < 2; ++kk) {
            const int ko = kk * 32 + lg * 8;
            bf16x8 af[4], bv[4];
#pragma unroll
            for (int m = 0; m < 4; ++m)
                af[m] = *(const bf16x8*)&As[(wr * 64 + m * 16 + lr) * 64 + ko];
#pragma unroll
            for (int n = 0; n < 4; ++n)
                bv[n] = *(const bf16x8*)&Bs[(wc * 64 + n * 16 + lr) * 64 + ko];
#pragma unroll
            for (int m = 0; m < 4; ++m)
#pragma unroll
                for (int n = 0; n < 4; ++n)
                    acc[m][n] = __builtin_amdgcn_mfma_f32_16x16x32_bf16(af[m], bv[n], acc[m][n], 0, 0, 0);
        }
        __syncthreads();
    }

    const int cbase = blockIdx.x * 128 + wc * 64;
    const int rbase = blockIdx.y * 128 + wr * 64;
#pragma unroll
    for (int n = 0; n < 4; ++n) {
        const int c = cbase + n * 16 + lr;
        const float bval = bias ? bias[c] : 0.0f;
#pragma unroll
        for (int m = 0; m < 4; ++m) {
#pragma unroll
            for (int j = 0; j < 4; ++j) {
                const int r = rbase + m * 16 + lg * 4 + j;
                if (r >= rows_valid) continue;
                float v = acc[m][n][j] + bval;
                if constexpr (GELU) v = 0.5f * v * (1.0f + erff(v * 0.70710678118654752f));
                long idx;
                if constexpr (OUTMODE == 1) {
                    const int pb = r / 576, pt = r - pb * 576;
                    v += pos[(long)(1 + pt) * DMODEL + c];
                    idx = (long)(pb * TOKENS + 1 + pt) * ldc + c;
                } else {
                    idx = (long)r * ldc + c;
                }
                if (Cf) Cf[idx] = v;
                if (Cb) Cb[idx] = __float2bfloat16(v);
            }
        }
    }
}

// ---------------------------------------------------------------------------
// BK=32 variant for FFN1 (round-11, kept).
// ---------------------------------------------------------------------------
template<bool GELU>
__global__ __launch_bounds__(256)
void gemm_bt32(const u16* __restrict__ A, int lda,
               const u16* __restrict__ Bt, int ldb,
               bf16* __restrict__ Cb, int ldc,
               const float* __restrict__ bias, int K, int rows_valid)
{
    __shared__ u16 As[128 * 32];
    __shared__ u16 Bs[128 * 32];
    const int tid  = threadIdx.x;
    const int w    = tid >> 6;
    const int lane = tid & 63;
    const u16* Ab = A + (long)blockIdx.y * 128 * lda;
    const u16* Bb = Bt + (long)blockIdx.x * 128 * ldb;
    const int wr = w >> 1, wc = w & 1;
    const int lr = lane & 15, lg = lane >> 4;
    f32x4 acc[4][4] = {};

    for (int kt = 0; kt < K; kt += 32) {
#pragma unroll
        for (int rd = 0; rd < 2; ++rd) {
            const int idx = rd * 256 + tid;
            const int row = idx >> 2, g = idx & 3;
            const int sg = g ^ ((row >> 1) & 3);
            __builtin_amdgcn_global_load_lds(
                (gas_ptr)(Ab + (long)row * lda + kt + sg * 8), (las_ptr)&As[idx * 8], 16, 0, 0);
            __builtin_amdgcn_global_load_lds(
                (gas_ptr)(Bb + (long)row * ldb + kt + sg * 8), (las_ptr)&Bs[idx * 8], 16, 0, 0);
        }
        __syncthreads();
        bf16x8 af[4], bv[4];
#pragma unroll
        for (int m = 0; m < 4; ++m) {
            const int r = wr * 64 + m * 16 + lr;
            af[m] = *(const bf16x8*)&As[r * 32 + (lg ^ ((r >> 1) & 3)) * 8];
        }
#pragma unroll
        for (int n = 0; n < 4; ++n) {
            const int r = wc * 64 + n * 16 + lr;
            bv[n] = *(const bf16x8*)&Bs[r * 32 + (lg ^ ((r >> 1) & 3)) * 8];
        }
#pragma unroll
        for (int m = 0; m < 4; ++m)
#pragma unroll
            for (int n = 0; n < 4; ++n)
                acc[m][n] = __builtin_amdgcn_mfma_f32_16x16x32_bf16(af[m], bv[n], acc[m][n], 0, 0, 0);
        __syncthreads();
    }

    const int cbase = blockIdx.x * 128 + wc * 64;
    const int rbase = blockIdx.y * 128 + wr * 64;
#pragma unroll
    for (int n = 0; n < 4; ++n) {
        const int c = cbase + n * 16 + lr;
        const float bval = bias ? bias[c] : 0.0f;
#pragma unroll
        for (int m = 0; m < 4; ++m) {
#pragma unroll
            for (int j = 0; j < 4; ++j) {
                const int r = rbase + m * 16 + lg * 4 + j;
                if (r >= rows_valid) continue;
                float v = acc[m][n][j] + bval;
                if constexpr (GELU) v = 0.5f * v * (1.0f + erff(v * 0.70710678118654752f));
                Cb[(long)r * ldc + c] = __float2bfloat16(v);
            }
        }
    }
}

// ---------------------------------------------------------------------------
// Fused proj + residual + LayerNorm (round-11, kept).
// ---------------------------------------------------------------------------
__global__ __launch_bounds__(512)
void proj_ln(const u16* __restrict__ A, const u16* __restrict__ Bt,
             const float* __restrict__ res,
             const float* __restrict__ g, const float* __restrict__ b,
             float* __restrict__ outf, bf16* __restrict__ outb, int Mrows)
{
    __shared__ u16 As[64 * 32];
    __shared__ u16 Bs[512 * 32];
    __shared__ float redS[4][64];
    __shared__ float redQ[4][64];
    const int tid = threadIdx.x, wid = tid >> 6, lane = tid & 63;
    const int wm = wid >> 2, wn = wid & 3;
    const int lr = lane & 15, lg = lane >> 4;
    const long row0 = (long)blockIdx.x * 64;
    const u16* Ab = A + row0 * DMODEL;
    f32x4 acc[2][8] = {};

    for (int kt = 0; kt < 512; kt += 32) {
#pragma unroll
        for (int rd = 0; rd < 4; ++rd) {
            const int idx = rd * 512 + tid;
            const int row = idx >> 2, gg = idx & 3;
            const int sg = gg ^ ((row >> 1) & 3);
            __builtin_amdgcn_global_load_lds(
                (gas_ptr)(Bt + (long)row * DMODEL + kt + sg * 8), (las_ptr)&Bs[idx * 8], 16, 0, 0);
        }
        if (tid < 256) {
            const int row = tid >> 2, gg = tid & 3;
            const int sg = gg ^ ((row >> 1) & 3);
            __builtin_amdgcn_global_load_lds(
                (gas_ptr)(Ab + (long)row * DMODEL + kt + sg * 8), (las_ptr)&As[tid * 8], 16, 0, 0);
        }
        __syncthreads();
        bf16x8 af[2], bv[8];
#pragma unroll
        for (int m = 0; m < 2; ++m) {
            const int r = wm * 32 + m * 16 + lr;
            af[m] = *(const bf16x8*)&As[r * 32 + (lg ^ ((r >> 1) & 3)) * 8];
        }
#pragma unroll
        for (int n = 0; n < 8; ++n) {
            const int r = wn * 128 + n * 16 + lr;
            bv[n] = *(const bf16x8*)&Bs[r * 32 + (lg ^ ((r >> 1) & 3)) * 8];
        }
#pragma unroll
        for (int m = 0; m < 2; ++m)
#pragma unroll
            for (int n = 0; n < 8; ++n)
                acc[m][n] = __builtin_amdgcn_mfma_f32_16x16x32_bf16(af[m], bv[n], acc[m][n], 0, 0, 0);
        __syncthreads();
    }

    float ps[2][4], pq[2][4];
#pragma unroll
    for (int m = 0; m < 2; ++m)
#pragma unroll
        for (int j = 0; j < 4; ++j) {
            const long r = row0 + wm * 32 + m * 16 + lg * 4 + j;
            const bool valid = r < Mrows;
            float s = 0.f, q = 0.f;
#pragma unroll
            for (int n = 0; n < 8; ++n) {
                float t = acc[m][n][j];
                if (valid) t += res[r * DMODEL + wn * 128 + n * 16 + lr];
                acc[m][n][j] = t;
                s += t; q += t * t;
            }
            ps[m][j] = s; pq[m][j] = q;
        }
#pragma unroll
    for (int o = 1; o < 16; o <<= 1)
#pragma unroll
        for (int m = 0; m < 2; ++m)
#pragma unroll
            for (int j = 0; j < 4; ++j) {
                ps[m][j] += __shfl_xor(ps[m][j], o);
                pq[m][j] += __shfl_xor(pq[m][j], o);
            }
    if (lr == 0) {
#pragma unroll
        for (int m = 0; m < 2; ++m)
#pragma unroll
            for (int j = 0; j < 4; ++j) {
                const int ri = wm * 32 + m * 16 + lg * 4 + j;
                redS[wn][ri] = ps[m][j];
                redQ[wn][ri] = pq[m][j];
            }
    }
    __syncthreads();
    if (tid < 64) {
        const float s = redS[0][tid] + redS[1][tid] + redS[2][tid] + redS[3][tid];
        const float q = redQ[0][tid] + redQ[1][tid] + redQ[2][tid] + redQ[3][tid];
        const float mean = s * (1.f / 512.f);
        const float var = q * (1.f / 512.f) - mean * mean;
        redS[0][tid] = mean;
        redQ[0][tid] = rsqrtf(var + 1e-5f);
    }
    __syncthreads();
#pragma unroll
    for (int m = 0; m < 2; ++m)
#pragma unroll
        for (int j = 0; j < 4; ++j) {
            const int ri = wm * 32 + m * 16 + lg * 4 + j;
            const long r = row0 + ri;
            if (r >= Mrows) continue;
            const float mean = redS[0][ri], rs = redQ[0][ri];
#pragma unroll
            for (int n = 0; n < 8; ++n) {
                const int c = wn * 128 + n * 16 + lr;
                const float o = (acc[m][n][j] - mean) * rs * g[c] + b[c];
                outf[r * DMODEL + c] = o;
                outb[r * DMODEL + c] = __float2bfloat16(o);
            }
        }
}

// ---------------------------------------------------------------------------
// 8-phase GEMM (round-8, refcheck'd). Used for FFN2 (K=2048).
// ---------------------------------------------------------------------------
template<int OUTMODE, bool GELU>
__global__ __launch_bounds__(512, 1)
void gemm8(const u16* __restrict__ A, int lda,
           const u16* __restrict__ Bt, int ldb,
           float* __restrict__ Cf, bf16* __restrict__ Cb, int ldc,
           const float* __restrict__ bias, const float* __restrict__ pos,
           int K, int rows_valid)
{
    __shared__ u16 Ash[2][2][256 * 32];
    __shared__ u16 Bsh[2][2][256 * 32];
    const int tid = threadIdx.x, wid = tid >> 6, lane = tid & 63;
    const int wm = wid >> 2, wn = wid & 3;
    const int lr = lane & 15, lg = lane >> 4;
    const u16* Ab = A + (long)blockIdx.y * 256 * lda;
    const u16* Bb = Bt + (long)blockIdx.x * 256 * ldb;
    const int srow = tid >> 2;
    const int soct = ((tid & 3) ^ (srow & 3)) * 8;
    const int slot8 = (lg ^ (lr & 3)) * 8;

    f32x4 acc[8][4] = {};

    auto stage = [&](u16* dst, const u16* src, int ld, int kt, int kh) {
#pragma unroll
        for (int i = 0; i < 2; ++i)
            __builtin_amdgcn_global_load_lds(
                (gas_ptr)(src + (long)(i * 128 + srow) * ld + kt * 64 + kh * 32 + soct),
                (las_ptr)(dst + (i * 512 + tid) * 8), 16, 0, 0);
    };

#define VMW(n) { asm volatile("s_waitcnt vmcnt(" #n ")" ::: "memory"); \
                 __builtin_amdgcn_sched_barrier(0); }
#define MFMA16(A0)                                                              \
    __builtin_amdgcn_s_setprio(1);                                             \
    _Pragma("unroll")                                                           \
    for (int m = 0; m < 4; ++m)                                                 \
        _Pragma("unroll")                                                       \
        for (int n = 0; n < 4; ++n)                                             \
            acc[(A0) + m][n] = __builtin_amdgcn_mfma_f32_16x16x32_bf16(         \
                af[m], bfr[n], acc[(A0) + m][n], 0, 0, 0);                      \
    __builtin_amdgcn_s_setprio(0);

    const int nt = K / 64;
    stage(&Ash[0][0][0], Ab, lda, 0, 0);
    stage(&Bsh[0][0][0], Bb, ldb, 0, 0);
    stage(&Ash[0][1][0], Ab, lda, 0, 1);
    stage(&Bsh[0][1][0], Bb, ldb, 0, 1);
    VMW(4);
    __builtin_amdgcn_s_barrier();

    for (int t = 0; t < nt; ++t) {
        const int db = t & 1;
        const bool nx = (t + 1 < nt);
        bf16x8 af[4], bfr[4];

#pragma unroll
        for (int n = 0; n < 4; ++n)
            bfr[n] = *(const bf16x8*)&Bsh[db][0][(wn * 64 + n * 16 + lr) * 32 + slot8];
#pragma unroll
        for (int m = 0; m < 4; ++m)
            af[m] = *(const bf16x8*)&Ash[db][0][(wm * 128 + m * 16 + lr) * 32 + slot8];
        if (nx) stage(&Ash[db ^ 1][0][0], Ab, lda, t + 1, 0);
        __builtin_amdgcn_s_barrier();
        MFMA16(0)
        __builtin_amdgcn_s_barrier();

#pragma unroll
        for (int m = 0; m < 4; ++m)
            af[m] = *(const bf16x8*)&Ash[db][0][(wm * 128 + 64 + m * 16 + lr) * 32 + slot8];
        if (nx) { stage(&Bsh[db ^ 1][0][0], Bb, ldb, t + 1, 0); VMW(4); }
        else    { VMW(0); }
        __builtin_amdgcn_s_barrier();
        MFMA16(4)
        __builtin_amdgcn_s_barrier();

#pragma unroll
        for (int n = 0; n < 4; ++n)
            bfr[n] = *(const bf16x8*)&Bsh[db][1][(wn * 64 + n * 16 + lr) * 32 + slot8];
#pragma unroll
        for (int m = 0; m < 4; ++m)
            af[m] = *(const bf16x8*)&Ash[db][1][(wm * 128 + m * 16 + lr) * 32 + slot8];
        if (nx) stage(&Ash[db ^ 1][1][0], Ab, lda, t + 1, 1);
        __builtin_amdgcn_s_barrier();
        MFMA16(0)
        __builtin_amdgcn_s_barrier();

#pragma unroll
        for (int m = 0; m < 4; ++m)
            af[m] = *(const bf16x8*)&Ash[db][1][(wm * 128 + 64 + m * 16 + lr) * 32 + slot8];
        if (nx) { stage(&Bsh[db ^ 1][1][0], Bb, ldb, t + 1, 1); VMW(4); }
        __builtin_amdgcn_s_barrier();
        MFMA16(4)
        __builtin_amdgcn_s_barrier();
    }
#undef MFMA16
#undef VMW

    const int cbase = blockIdx.x * 256 + wn * 64;
    const int rbase = blockIdx.y * 256 + wm * 128;
#pragma unroll
    for (int n = 0; n < 4; ++n) {
        const int c = cbase + n * 16 + lr;
        const float bval = bias ? bias[c] : 0.0f;
#pragma unroll
        for (int a = 0; a < 8; ++a) {
#pragma unroll
            for (int j = 0; j < 4; ++j) {
                const int r = rbase + a * 16 + lg * 4 + j;
                if (r >= rows_valid) continue;
                float v = acc[a][n][j] + bval;
                if constexpr (GELU) v = 0.5f * v * (1.0f + erff(v * 0.70710678118654752f));
                long idx;
                if constexpr (OUTMODE == 1) {
                    const int pb = r / 576, pt = r - pb * 576;
                    v += pos[(long)(1 + pt) * DMODEL + c];
                    idx = (long)(pb * TOKENS + 1 + pt) * ldc + c;
                } else {
                    idx = (long)r * ldc + c;
                }
                if (Cf) Cf[idx] = v;
                if (Cb) Cb[idx] = __float2bfloat16(v);
            }
        }
    }
}

// ---------------------------------------------------------------------------
// Fused flash attention v3: kv-tile = 64, K/V double-buffered, 2-deep counted
// vmcnt pipeline (stage t+2 after tile t, wait certifies t+1), wave-private
// P buffer (no mid-tile barriers), XOR-swizzled K/V/P LDS.
// Grid: (5 q-tiles, NP pairs). qkv layout: [row][kk*512 + h*128 + d].
// ---------------------------------------------------------------------------
__global__ __launch_bounds__(256, 2)
void attn_flash(const u16* __restrict__ qkv, const u16* __restrict__ vhT,
                bf16* __restrict__ ob)
{
    __shared__ u16 Ksh[2][64 * 128];   // 32 KB  [kv][d], swizzled octets
    __shared__ u16 Vsh[2][128 * 64];   // 32 KB  [d][kv], swizzled octets
    __shared__ u16 Psh[128 * 64];      // 16 KB  wave-private rows
    const int tid = threadIdx.x;
    const int w = tid >> 6, lane = tid & 63;
    const int lr = lane & 15, lg = lane >> 4;
    const int pair = blockIdx.y;
    const int b = pair >> 2, h = pair & 3;
    const int q0 = blockIdx.x * 128;
    const long rowbase = (long)b * TOKENS;
    const int swrd = lr & 7;

    const u16* kg = qkv + rowbase * 1536 + 512 + h * 128;
    const u16* vg = vhT + (long)pair * 128 * TPAD;

    auto stageK = [&](int buf, int t) {
#pragma unroll
        for (int i = 0; i < 4; ++i) {
            const int slot = i * 256 + tid;           // 0..1023
            const int row = slot >> 4, s = slot & 15;
            const int so = (s & 8) | ((s & 7) ^ (row & 7));
            __builtin_amdgcn_global_load_lds(
                (gas_ptr)(kg + (long)(t * 64 + row) * 1536 + so * 8),
                (las_ptr)&Ksh[buf][slot * 8], 16, 0, 0);
        }
    };
    auto stageV = [&](int buf, int t) {
#pragma unroll
        for (int i = 0; i < 4; ++i) {
            const int slot = i * 256 + tid;           // 0..1023
            const int row = slot >> 3, s = slot & 7;  // row = d
            const int so = s ^ (row & 7);
            __builtin_amdgcn_global_load_lds(
                (gas_ptr)(vg + (long)row * TPAD + t * 64 + so * 8),
                (las_ptr)&Vsh[buf][slot * 8], 16, 0, 0);
        }
    };

    // Q fragments in registers
    bf16x8 qf[2][4];
#pragma unroll
    for (int m = 0; m < 2; ++m)
#pragma unroll
        for (int kf = 0; kf < 4; ++kf) {
            const long r = rowbase + q0 + w * 32 + m * 16 + lr;
            qf[m][kf] = *(const bf16x8*)&qkv[r * 1536 + h * 128 + kf * 32 + lg * 8];
        }

    float mrun[2][4], lrun[2][4];
#pragma unroll
    for (int m = 0; m < 2; ++m)
#pragma unroll
        for (int j = 0; j < 4; ++j) { mrun[m][j] = -1e30f; lrun[m][j] = 0.f; }
    f32x4 oacc[2][8] = {};

    constexpr int NT = TPAD / 64;   // 10
    // prologue: 2 tiles in flight; certify t0 (8 loads/thread/tile)
    stageK(0, 0); stageV(0, 0);
    stageK(1, 1); stageV(1, 1);
    asm volatile("s_waitcnt vmcnt(8)" ::: "memory");
    __builtin_amdgcn_sched_barrier(0);
    __builtin_amdgcn_s_barrier();

    for (int t = 0; t < NT; ++t) {
        const int cur = t & 1;

        // ---- S = Q K^T (32q x 64kv per wave) ----
        f32x4 s[2][4] = {};
#pragma unroll
        for (int kf = 0; kf < 4; ++kf) {
            const int o = kf * 4 + lg;                        // octet 0..15
            const int so = ((o & 8) | ((o & 7) ^ swrd)) * 8;
            bf16x8 bv[4];
#pragma unroll
            for (int n = 0; n < 4; ++n)
                bv[n] = *(const bf16x8*)&Ksh[cur][(n * 16 + lr) * 128 + so];
            __builtin_amdgcn_s_setprio(1);
#pragma unroll
            for (int m = 0; m < 2; ++m)
#pragma unroll
                for (int n = 0; n < 4; ++n)
                    s[m][n] = __builtin_amdgcn_mfma_f32_16x16x32_bf16(qf[m][kf], bv[n], s[m][n], 0, 0, 0);
            __builtin_amdgcn_s_setprio(0);
        }

        // ---- online softmax ----
        float sc[2][4];
#pragma unroll
        for (int m = 0; m < 2; ++m)
#pragma unroll
            for (int jj = 0; jj < 4; ++jj) {
                float mx = mrun[m][jj];
#pragma unroll
                for (int n = 0; n < 4; ++n) {
                    const int col = t * 64 + n * 16 + lr;
                    float v = s[m][n][jj] * SM_SCALE;
                    v = (col < TOKENS) ? v : -1e30f;
                    s[m][n][jj] = v;
                    mx = fmaxf(mx, v);
                }
#pragma unroll
                for (int o = 1; o < 16; o <<= 1) mx = fmaxf(mx, __shfl_xor(mx, o));
                const float f = __expf(mrun[m][jj] - mx);
                sc[m][jj] = f;
                float sum = 0.f;
#pragma unroll
                for (int n = 0; n < 4; ++n) {
                    const float p = __expf(s[m][n][jj] - mx);
                    s[m][n][jj] = p;
                    sum += p;
                }
#pragma unroll
                for (int o = 1; o < 16; o <<= 1) sum += __shfl_xor(sum, o);
                lrun[m][jj] = lrun[m][jj] * f + sum;
                mrun[m][jj] = mx;
            }
#pragma unroll
        for (int m = 0; m < 2; ++m)
#pragma unroll
            for (int n = 0; n < 8; ++n)
#pragma unroll
                for (int jj = 0; jj < 4; ++jj) oacc[m][n][jj] *= sc[m][jj];

        // ---- P -> Psh (wave-private rows; swizzled octets) ----
#pragma unroll
        for (int m = 0; m < 2; ++m)
#pragma unroll
            for (int jj = 0; jj < 4; ++jj) {
                const int prow = w * 32 + m * 16 + lg * 4 + jj;
                const int p7 = prow & 7;
#pragma unroll
                for (int n = 0; n < 4; ++n) {
                    const int c = n * 16 + lr;
                    Psh[prow * 64 + (((c >> 3) ^ p7) << 3) + (c & 7)] = f2b(s[m][n][jj]);
                }
            }

        // ---- O += P V (K=64: kf 0..1) ----
#pragma unroll
        for (int kf = 0; kf < 2; ++kf) {
            const int so = ((kf * 4 + lg) ^ swrd) * 8;        // octet 0..7
            bf16x8 pa[2];
#pragma unroll
            for (int m = 0; m < 2; ++m)
                pa[m] = *(const bf16x8*)&Psh[(w * 32 + m * 16 + lr) * 64 + so];
            __builtin_amdgcn_s_setprio(1);
#pragma unroll
            for (int n = 0; n < 8; ++n) {
                const bf16x8 vb = *(const bf16x8*)&Vsh[cur][(n * 16 + lr) * 64 + so];
#pragma unroll
                for (int m = 0; m < 2; ++m)
                    oacc[m][n] = __builtin_amdgcn_mfma_f32_16x16x32_bf16(pa[m], vb, oacc[m][n], 0, 0, 0);
            }
            __builtin_amdgcn_s_setprio(0);
        }

        // ---- pipeline bottom: all waves done with buf[cur]; refill it ----
        __builtin_amdgcn_s_barrier();
        if (t + 2 < NT) { stageK(cur, t + 2); stageV(cur, t + 2); }
        if (t + 1 < NT) {
            if (t + 2 < NT) { asm volatile("s_waitcnt vmcnt(8)" ::: "memory"); }
            else            { asm volatile("s_waitcnt vmcnt(0)" ::: "memory"); }
            __builtin_amdgcn_sched_barrier(0);
        }
        __builtin_amdgcn_s_barrier();   // all waves certified tile t+1
    }

    // epilogue
#pragma unroll
    for (int m = 0; m < 2; ++m)
#pragma unroll
        for (int jj = 0; jj < 4; ++jj) {
            const float inv = 1.f / lrun[m][jj];
            const int q = q0 + w * 32 + m * 16 + lg * 4 + jj;
            if (q >= TOKENS) continue;
#pragma unroll
            for (int n = 0; n < 8; ++n)
                ob[(rowbase + q) * DMODEL + h * 128 + n * 16 + lr] =
                    __float2bfloat16(oacc[m][n][jj] * inv);
        }
}

// ---------------------------------------------------------------------------
// Patch-embed weight transpose (once).
// ---------------------------------------------------------------------------
__global__ __launch_bounds__(256)
void wtrans(const float* __restrict__ W, bf16* __restrict__ WT, int K, int N)
{
    __shared__ float tile[32][33];
    const int n0 = blockIdx.x * 32, k0 = blockIdx.y * 32;
    const int tx = threadIdx.x & 31, ty = threadIdx.x >> 5;
#pragma unroll
    for (int i = 0; i < 4; ++i)
        tile[ty + i * 8][tx] = W[(long)(k0 + ty + i * 8) * N + n0 + tx];
    __syncthreads();
#pragma unroll
    for (int i = 0; i < 4; ++i)
        WT[(long)(n0 + ty + i * 8) * K + k0 + tx] = __float2bfloat16(tile[tx][ty + i * 8]);
}

// ---------------------------------------------------------------------------
// Layer weight transpose (round-11, kept).
// ---------------------------------------------------------------------------
__global__ __launch_bounds__(256)
void wtrans_layers(const float* __restrict__ Wqkv, const float* __restrict__ W0,
                   const float* __restrict__ W1, const float* __restrict__ W2,
                   bf16* __restrict__ out, int layer0)
{
    const int bb = blockIdx.x;
    const int sl = bb / 3072;
    const int l = layer0 + sl;
    int t = bb % 3072;
    bf16* base = out + (long)sl * LAYER_W;
    const float* W; bf16* WT; int K, N; bool perm = false;
    if (t < 768)       {            W = Wqkv + (long)l * 512 * 1536; WT = base;           K = 512;  N = 1536; perm = true; }
    else if (t < 1024) { t -= 768;  W = W0   + (long)l * 512 * 512;  WT = base + 786432;  K = 512;  N = 512;  }
    else if (t < 2048) { t -= 1024; W = W1   + (long)l * 512 * 2048; WT = base + 1048576; K = 512;  N = 2048; }
    else               { t -= 2048; W = W2   + (long)l * 2048 * 512; WT = base + 2097152; K = 2048; N = 512;  }
    const int nx = N / 32;
    const int n0 = (t % nx) * 32, k0 = (t / nx) * 32;
    __shared__ float tile[32][33];
    const int tx = threadIdx.x & 31, ty = threadIdx.x >> 5;
#pragma unroll
    for (int i = 0; i < 4; ++i)
        tile[ty + i * 8][tx] = W[(long)(k0 + ty + i * 8) * N + n0 + tx];
    __syncthreads();
#pragma unroll
    for (int i = 0; i < 4; ++i) {
        int n = n0 + ty + i * 8;
        if (perm) {
            const int d = n / 12, rr = n % 12;
            n = (rr >> 2) * 512 + (rr & 3) * 128 + d;
        }
        WT[(long)n * K + k0 + tx] = __float2bfloat16(tile[tx][ty + i * 8]);
    }
}

// ---------------------------------------------------------------------------
__global__ __launch_bounds__(64)
void patch_gather(const float* __restrict__ img, bf16* __restrict__ pat)
{
    const int bid = blockIdx.x;
    const int x  = bid % 24;
    const int p1 = (bid / 24) % 16;
    const int b  = bid / (24 * 16);
    __shared__ bf16 lds[24][48];
    const int lane = threadIdx.x;
    const int h = p1 * 24 + x;
    for (int c = 0; c < 3; ++c) {
        const float* row = img + ((long)(b * 3 + c) * 384 + h) * 384;
#pragma unroll
        for (int i = 0; i < 6; ++i) {
            const int wpix = lane + i * 64;
            const float v = row[wpix];
            const int y = wpix % 24, p2 = wpix / 24;
            lds[y][p2 * 3 + c] = __float2bfloat16(v);
        }
    }
    __syncthreads();
    for (int idx = lane; idx < 24 * 48; idx += 64) {
        const int y = idx / 48, j = idx % 48;
        pat[(long)(b * 576 + x * 24 + y) * 768 + p1 * 48 + j] = lds[y][j];
    }
}

__global__ __launch_bounds__(256)
void clsfill(const float* __restrict__ cls, const float* __restrict__ pos,
             float* __restrict__ tokf, bf16* __restrict__ xb)
{
    const int i = blockIdx.x * 256 + threadIdx.x;
    const int b = i >> 9, d = i & 511;
    const float v = cls[d] + pos[d];
    tokf[(long)b * TOKENS * DMODEL + d] = v;
    xb[(long)b * TOKENS * DMODEL + d] = __float2bfloat16(v);
}

__global__ __launch_bounds__(256)
void repack_v(const u16* __restrict__ qkv, u16* __restrict__ vhT)
{
    __shared__ u16 lds[64][136];
    const int bid = blockIdx.x;
    const int tt = bid % 10, pair = bid / 10;
    const int b = pair >> 2, h = pair & 3;
    const int tid = threadIdx.x;
    const int tl = tid >> 2, seg = tid & 3;
    const long row = (long)b * TOKENS + tt * 64 + tl;
    const u16* src = qkv + row * 1536 + 1024 + h * 128 + seg * 32;
#pragma unroll
    for (int u = 0; u < 4; ++u)
        *(uint4*)&lds[tl][seg * 32 + u * 8] = *(const uint4*)&src[u * 8];
    __syncthreads();
    const int d = tid >> 1, th = (tid & 1) * 32;
    u16* dst = vhT + ((long)pair * 128 + d) * TPAD + tt * 64 + th;
#pragma unroll
    for (int blk = 0; blk < 4; ++blk) {
        uint4 pk; u16* pp = (u16*)&pk;
#pragma unroll
        for (int j = 0; j < 8; ++j) {
            const int t = tt * 64 + th + blk * 8 + j;
            pp[j] = (t < TOKENS) ? lds[th + blk * 8 + j][d] : (u16)0;
        }
        *(uint4*)&dst[blk * 8] = pk;
    }
}

// y = LN(xin + res)*g + b  (LN2)
__global__ __launch_bounds__(256)
void resln(const float* __restrict__ xin, const float* __restrict__ res,
           const float* __restrict__ g, const float* __restrict__ b,
           float* __restrict__ outf, bf16* __restrict__ outb, int nrows)
{
    const int row = blockIdx.x * 4 + (threadIdx.x >> 6);
    if (row >= nrows) return;
    const int lane = threadIdx.x & 63;
    const float* p1 = xin + (long)row * DMODEL;
    const float* p2 = res + (long)row * DMODEL;
    float v[8];
    float s = 0.f;
#pragma unroll
    for (int i = 0; i < 8; ++i) { v[i] = p1[lane + i * 64] + p2[lane + i * 64]; s += v[i]; }
#pragma unroll
    for (int o = 32; o; o >>= 1) s += __shfl_xor(s, o);
    const float mean = s * (1.f / 512.f);
    float q = 0.f;
#pragma unroll
    for (int i = 0; i < 8; ++i) { const float d = v[i] - mean; q += d * d; }
#pragma unroll
    for (int o = 32; o; o >>= 1) q += __shfl_xor(q, o);
    const float rs = rsqrtf(q * (1.f / 512.f) + 1e-5f);
#pragma unroll
    for (int i = 0; i < 8; ++i) {
        const int c = lane + i * 64;
        const float o = (v[i] - mean) * rs * g[c] + b[c];
        outf[(long)row * DMODEL + c] = o;
        outb[(long)row * DMODEL + c] = __float2bfloat16(o);
    }
}

__global__ __launch_bounds__(64)
void head_k(const float* __restrict__ tokf, const float* __restrict__ Wh,
            const float* __restrict__ bh, float* __restrict__ out)
{
    const int b = blockIdx.x;
    const int lane = threadIdx.x;
    const float* x = tokf + (long)b * TOKENS * DMODEL;
    float acc[10] = {};
#pragma unroll
    for (int i = 0; i < 8; ++i) {
        const int d = lane + i * 64;
        const float xv = x[d];
        const float* wr = Wh + (long)d * 10;
#pragma unroll
        for (int c = 0; c < 10; ++c) acc[c] += xv * wr[c];
    }
#pragma unroll
    for (int c = 0; c < 10; ++c)
#pragma unroll
        for (int o = 32; o; o >>= 1) acc[c] += __shfl_xor(acc[c], o);
    if (lane == 0) {
#pragma unroll
        for (int c = 0; c < 10; ++c) out[b * 10 + c] = acc[c] + bh[c];
    }
}

// ---------------------------------------------------------------------------
extern "C" void kernel_launch(void* const* d_in, const int* in_sizes, int n_in,
                              void* d_out, int out_size, void* d_ws, size_t ws_size,
                              hipStream_t stream)
{
    (void)in_sizes; (void)n_in; (void)out_size;
    const float* img    = (const float*)d_in[0];
    const float* Wpatch = (const float*)d_in[1];
    const float* bpatch = (const float*)d_in[2];
    const float* clstk  = (const float*)d_in[3];
    const float* pos    = (const float*)d_in[4];
    const float* Wqkv   = (const float*)d_in[5];
    const float* W0     = (const float*)d_in[6];
    const float* g1     = (const float*)d_in[7];
    const float* b1     = (const float*)d_in[8];
    const float* g2     = (const float*)d_in[9];
    const float* b2     = (const float*)d_in[10];
    const float* W1     = (const float*)d_in[11];
    const float* bb1    = (const float*)d_in[12];
    const float* W2     = (const float*)d_in[13];
    const float* bb2    = (const float*)d_in[14];
    const float* Whead  = (const float*)d_in[15];
    const float* bhead  = (const float*)d_in[16];

    // ---- config ladder: (batch chunk, weight buffers) ----
    static const int cand[7][2] = {{32,6},{32,1},{16,1},{8,1},{4,1},{2,1},{1,1}};
    int Bc = 0, nW = 1;
    size_t o_tokf=0, o_xb=0, o_R1=0, o_R2=0, o_ob=0, o_wp=0, o_wr=0;
    for (int ci = 0; ci < 7; ++ci) {
        const int bc = cand[ci][0], nw = cand[ci][1];
        const long Mrows = (long)bc * TOKENS;
        const long Mpad  = ((Mrows + 255) / 256) * 256;
        size_t off = 0;
        auto take = [&](size_t sz) { size_t o = off; off += (sz + 255) & ~(size_t)255; return o; };
        size_t t_tokf = take((size_t)Mpad * 512 * 4);
        size_t t_xb   = take((size_t)Mpad * 512 * 2);
        size_t t_R1   = take((size_t)Mpad * 2048 * 2);          // pat | qkv | h1b
        size_t r2a = (size_t)bc * 4 * TPAD * 128 * 2;           // vhT
        size_t r2b = (size_t)Mpad * 512 * 4;                    // t1 (f32)
        size_t t_R2 = take(r2a > r2b ? r2a : r2b);
        size_t t_ob   = take((size_t)Mpad * 512 * 2);
        size_t t_wp   = take((size_t)512 * 768 * 2);
        size_t t_wr   = take((size_t)nw * LAYER_W * 2);
        if (off <= ws_size) {
            Bc = bc; nW = nw;
            o_tokf=t_tokf; o_xb=t_xb; o_R1=t_R1; o_R2=t_R2; o_ob=t_ob; o_wp=t_wp; o_wr=t_wr;
            break;
        }
    }
    if (Bc == 0) return;

    const long Mrows = (long)Bc * TOKENS;
    const long Mpad  = ((Mrows + 255) / 256) * 256;
    const int  NP    = Bc * 4;
    const int  gy128 = (int)(Mpad / 128);
    const int  gy256 = (int)(Mpad / 256);
    const int  nproj = (int)((Mrows + 63) / 64);
    const long patRows = ((long)Bc * 576 + 127) / 128 * 128;

    char* base = (char*)d_ws;
    float* tokf = (float*)(base + o_tokf);
    bf16*  xb   = (bf16*)(base + o_xb);
    char*  R1   = base + o_R1;
    char*  R2   = base + o_R2;
    bf16*  ob   = (bf16*)(base + o_ob);
    bf16*  wpT  = (bf16*)(base + o_wp);
    bf16*  wAll = (bf16*)(base + o_wr);

    u16*  qkvb = (u16*)R1;
    bf16* pat  = (bf16*)R1;
    u16*  h1b  = (u16*)R1;
    u16*  vhT  = (u16*)R2;
    float* t1  = (float*)R2;

    wtrans<<<dim3(512 / 32, 768 / 32), 256, 0, stream>>>(Wpatch, wpT, 768, 512);
    if (nW == 6)
        wtrans_layers<<<6 * 3072, 256, 0, stream>>>(Wqkv, W0, W1, W2, wAll, 0);

    const int nchunks = 32 / Bc;
    for (int ch = 0; ch < nchunks; ++ch) {
        const float* img_c = img + (long)ch * Bc * 3 * 384 * 384;

        hipMemsetAsync(xb, 0, (size_t)Mpad * 512 * 2, stream);   // pad rows -> exact 0
        clsfill<<<Bc * 2, 256, 0, stream>>>(clstk, pos, tokf, xb);
        patch_gather<<<Bc * 16 * 24, 64, 0, stream>>>(img_c, pat);
        gemm_bt<1, false><<<dim3(4, (int)(patRows / 128)), 256, 0, stream>>>(
            (const u16*)pat, 768, (const u16*)wpT, 768,
            tokf, xb, 512, bpatch, pos, 768, Bc * 576);

        for (int l = 0; l < 6; ++l) {
            const bf16* wL = wAll + (nW == 6 ? (long)l * LAYER_W : 0);
            if (nW == 1)
                wtrans_layers<<<3072, 256, 0, stream>>>(Wqkv, W0, W1, W2, wAll, l);
            const u16* wqkvT = (const u16*)wL;
            const u16* w0T   = (const u16*)(wL + 786432);
            const u16* w1T   = (const u16*)(wL + 1048576);
            const u16* w2T   = (const u16*)(wL + 2097152);

            // qkv = x @ Wqkv  (permuted cols: kk*512 + h*128 + d)
            gemm_bt<0, false><<<dim3(12, gy128), 256, 0, stream>>>(
                (const u16*)xb, 512, wqkvT, 512,
                nullptr, (bf16*)qkvb, 1536, nullptr, nullptr, 512, (int)Mpad);

            repack_v<<<NP * 10, 256, 0, stream>>>(qkvb, vhT);
            attn_flash<<<dim3(5, NP), 256, 0, stream>>>(qkvb, vhT, ob);

            // fused proj + residual + LN1 -> tokf, xb
            proj_ln<<<nproj, 512, 0, stream>>>(
                (const u16*)ob, w0T, tokf, g1 + l * 512, b1 + l * 512,
                tokf, xb, (int)Mrows);

            // h1 = gelu(y @ W1 + bb1)
            gemm_bt32<true><<<dim3(16, gy128), 256, 0, stream>>>(
                (const u16*)xb, 512, w1T, 512,
                (bf16*)h1b, 2048, bb1 + l * 2048, 512, (int)Mrows);

            // t1 = h1 @ W2 + bb2  (K=2048 -> 8-phase pipeline)
            gemm8<0, false><<<dim3(2, gy256), 512, 0, stream>>>(
                (const u16*)h1b, 2048, w2T, 2048,
                t1, nullptr, 512, bb2 + l * 512, nullptr, 2048, (int)Mrows);
            // x = LN(t1 + y) -> tokf, xb
            resln<<<(int)((Mrows + 3) / 4), 256, 0, stream>>>(
                t1, tokf, g2 + l * 512, b2 + l * 512, tokf, xb, (int)Mrows);
        }

        head_k<<<Bc, 64, 0, stream>>>(tokf, Whead, bhead, (float*)d_out + (long)ch * Bc * 10);
    }
}

// Round 14
// 2645.978 us; speedup vs baseline: 1.3506x; 1.0703x over previous
//
#include <hip/hip_runtime.h>
#include <hip/hip_bf16.h>

// ViT forward, MI355X. Round-13 structure; FFN1 packed uint2 stores (kills 2x
// write amplification; w2T k-permuted to compensate, round-6-verified), qkv on
// the BK=32 kernel. Pipelined flash attention (round-13). proj+LN fused.

typedef unsigned short u16;
typedef __hip_bfloat16 bf16;
typedef __bf16 bf16x8 __attribute__((ext_vector_type(8)));
typedef float f32x4 __attribute__((ext_vector_type(4)));

typedef const __attribute__((address_space(1))) void* gas_ptr;
typedef __attribute__((address_space(3))) void* las_ptr;

#define TOKENS 577
#define TPAD   640
#define DMODEL 512
#define SM_SCALE 0.08838834764831845f   /* 128^-0.5 */
#define LAYER_W 3145728l                /* bf16 elems per layer's weights */

static __device__ __forceinline__ u16 f2b(float v) {
    bf16 t = __float2bfloat16(v);
    return *(u16*)&t;
}

// ---------------------------------------------------------------------------
// Round-3 GEMM (patch embed only now): 128x128 tile, BK=64.
// OUTMODE 0: plain. 1: patch-embed epilogue (row remap b*577+1+t, +pos).
// ---------------------------------------------------------------------------
template<int OUTMODE, bool GELU>
__global__ __launch_bounds__(256)
void gemm_bt(const u16* __restrict__ A, int lda,
             const u16* __restrict__ Bt, int ldb,
             float* __restrict__ Cf, bf16* __restrict__ Cb, int ldc,
             const float* __restrict__ bias, const float* __restrict__ pos,
             int K, int rows_valid)
{
    __shared__ u16 As[128 * 64];
    __shared__ u16 Bs[128 * 64];
    const int tid  = threadIdx.x;
    const int w    = tid >> 6;
    const int lane = tid & 63;
    const u16* Ab = A + (long)blockIdx.y * 128 * lda;
    const u16* Bb = Bt + (long)blockIdx.x * 128 * ldb;
    const int srow = w * 8 + (lane >> 3);
    const int scol = (lane & 7) * 8;
    const int wr = w >> 1, wc = w & 1;
    const int lr = lane & 15, lg = lane >> 4;
    f32x4 acc[4][4] = {};

    for (int kt = 0; kt < K; kt += 64) {
#pragma unroll
        for (int i = 0; i < 4; ++i) {
            const u16* ag = Ab + (long)(i * 32 + srow) * lda + kt + scol;
            const u16* bg = Bb + (long)(i * 32 + srow) * ldb + kt + scol;
            __builtin_amdgcn_global_load_lds((gas_ptr)ag, (las_ptr)&As[(i * 32 + w * 8) * 64], 16, 0, 0);
            __builtin_amdgcn_global_load_lds((gas_ptr)bg, (las_ptr)&Bs[(i * 32 + w * 8) * 64], 16, 0, 0);
        }
        __syncthreads();
#pragma unroll
        for (int kk = 0; kk < 2; ++kk) {
            const int ko = kk * 32 + lg * 8;
            bf16x8 af[4], bv[4];
#pragma unroll
            for (int m = 0; m < 4; ++m)
                af[m] = *(const bf16x8*)&As[(wr * 64 + m * 16 + lr) * 64 + ko];
#pragma unroll
            for (int n = 0; n < 4; ++n)
                bv[n] = *(const bf16x8*)&Bs[(wc * 64 + n * 16 + lr) * 64 + ko];
#pragma unroll
            for (int m = 0; m < 4; ++m)
#pragma unroll
                for (int n = 0; n < 4; ++n)
                    acc[m][n] = __builtin_amdgcn_mfma_f32_16x16x32_bf16(af[m], bv[n], acc[m][n], 0, 0, 0);
        }
        __syncthreads();
    }

    const int cbase = blockIdx.x * 128 + wc * 64;
    const int rbase = blockIdx.y * 128 + wr * 64;
#pragma unroll
    for (int n = 0; n < 4; ++n) {
        const int c = cbase + n * 16 + lr;
        const float bval = bias ? bias[c] : 0.0f;
#pragma unroll
        for (int m = 0; m < 4; ++m) {
#pragma unroll
            for (int j = 0; j < 4; ++j) {
                const int r = rbase + m * 16 + lg * 4 + j;
                if (r >= rows_valid) continue;
                float v = acc[m][n][j] + bval;
                if constexpr (GELU) v = 0.5f * v * (1.0f + erff(v * 0.70710678118654752f));
                long idx;
                if constexpr (OUTMODE == 1) {
                    const int pb = r / 576, pt = r - pb * 576;
                    v += pos[(long)(1 + pt) * DMODEL + c];
                    idx = (long)(pb * TOKENS + 1 + pt) * ldc + c;
                } else {
                    idx = (long)r * ldc + c;
                }
                if (Cf) Cf[idx] = v;
                if (Cb) Cb[idx] = __float2bfloat16(v);
            }
        }
    }
}

// ---------------------------------------------------------------------------
// BK=32 GEMM (FFN1 + qkv). PACKED: column-interleaved uint2 store
// (phys col = cbase + lr*4 + n; consumer compensates via w2T k-perm).
// ---------------------------------------------------------------------------
template<bool GELU, bool PACKED>
__global__ __launch_bounds__(256)
void gemm_bt32(const u16* __restrict__ A, int lda,
               const u16* __restrict__ Bt, int ldb,
               bf16* __restrict__ Cb, int ldc,
               const float* __restrict__ bias, int K, int rows_valid)
{
    __shared__ u16 As[128 * 32];
    __shared__ u16 Bs[128 * 32];
    const int tid  = threadIdx.x;
    const int w    = tid >> 6;
    const int lane = tid & 63;
    const u16* Ab = A + (long)blockIdx.y * 128 * lda;
    const u16* Bb = Bt + (long)blockIdx.x * 128 * ldb;
    const int wr = w >> 1, wc = w & 1;
    const int lr = lane & 15, lg = lane >> 4;
    f32x4 acc[4][4] = {};

    for (int kt = 0; kt < K; kt += 32) {
#pragma unroll
        for (int rd = 0; rd < 2; ++rd) {
            const int idx = rd * 256 + tid;
            const int row = idx >> 2, g = idx & 3;
            const int sg = g ^ ((row >> 1) & 3);
            __builtin_amdgcn_global_load_lds(
                (gas_ptr)(Ab + (long)row * lda + kt + sg * 8), (las_ptr)&As[idx * 8], 16, 0, 0);
            __builtin_amdgcn_global_load_lds(
                (gas_ptr)(Bb + (long)row * ldb + kt + sg * 8), (las_ptr)&Bs[idx * 8], 16, 0, 0);
        }
        __syncthreads();
        bf16x8 af[4], bv[4];
#pragma unroll
        for (int m = 0; m < 4; ++m) {
            const int r = wr * 64 + m * 16 + lr;
            af[m] = *(const bf16x8*)&As[r * 32 + (lg ^ ((r >> 1) & 3)) * 8];
        }
#pragma unroll
        for (int n = 0; n < 4; ++n) {
            const int r = wc * 64 + n * 16 + lr;
            bv[n] = *(const bf16x8*)&Bs[r * 32 + (lg ^ ((r >> 1) & 3)) * 8];
        }
#pragma unroll
        for (int m = 0; m < 4; ++m)
#pragma unroll
            for (int n = 0; n < 4; ++n)
                acc[m][n] = __builtin_amdgcn_mfma_f32_16x16x32_bf16(af[m], bv[n], acc[m][n], 0, 0, 0);
        __syncthreads();
    }

    const int cbase = blockIdx.x * 128 + wc * 64;
    const int rbase = blockIdx.y * 128 + wr * 64;
    float bval[4];
#pragma unroll
    for (int n = 0; n < 4; ++n) bval[n] = bias ? bias[cbase + n * 16 + lr] : 0.0f;

    if constexpr (PACKED) {
#pragma unroll
        for (int m = 0; m < 4; ++m) {
#pragma unroll
            for (int j = 0; j < 4; ++j) {
                const int r = rbase + m * 16 + lg * 4 + j;
                if (r >= rows_valid) continue;
                u16 pk[4];
#pragma unroll
                for (int n = 0; n < 4; ++n) {
                    float v = acc[m][n][j] + bval[n];
                    if constexpr (GELU) v = 0.5f * v * (1.0f + erff(v * 0.70710678118654752f));
                    pk[n] = f2b(v);
                }
                *(uint2*)&Cb[(long)r * ldc + cbase + lr * 4] = *(uint2*)pk;
            }
        }
    } else {
#pragma unroll
        for (int n = 0; n < 4; ++n) {
            const int c = cbase + n * 16 + lr;
#pragma unroll
            for (int m = 0; m < 4; ++m) {
#pragma unroll
                for (int j = 0; j < 4; ++j) {
                    const int r = rbase + m * 16 + lg * 4 + j;
                    if (r >= rows_valid) continue;
                    float v = acc[m][n][j] + bval[n];
                    if constexpr (GELU) v = 0.5f * v * (1.0f + erff(v * 0.70710678118654752f));
                    Cb[(long)r * ldc + c] = __float2bfloat16(v);
                }
            }
        }
    }
}

// ---------------------------------------------------------------------------
// Fused proj + residual + LayerNorm (round-11, kept).
// ---------------------------------------------------------------------------
__global__ __launch_bounds__(512)
void proj_ln(const u16* __restrict__ A, const u16* __restrict__ Bt,
             const float* __restrict__ res,
             const float* __restrict__ g, const float* __restrict__ b,
             float* __restrict__ outf, bf16* __restrict__ outb, int Mrows)
{
    __shared__ u16 As[64 * 32];
    __shared__ u16 Bs[512 * 32];
    __shared__ float redS[4][64];
    __shared__ float redQ[4][64];
    const int tid = threadIdx.x, wid = tid >> 6, lane = tid & 63;
    const int wm = wid >> 2, wn = wid & 3;
    const int lr = lane & 15, lg = lane >> 4;
    const long row0 = (long)blockIdx.x * 64;
    const u16* Ab = A + row0 * DMODEL;
    f32x4 acc[2][8] = {};

    for (int kt = 0; kt < 512; kt += 32) {
#pragma unroll
        for (int rd = 0; rd < 4; ++rd) {
            const int idx = rd * 512 + tid;
            const int row = idx >> 2, gg = idx & 3;
            const int sg = gg ^ ((row >> 1) & 3);
            __builtin_amdgcn_global_load_lds(
                (gas_ptr)(Bt + (long)row * DMODEL + kt + sg * 8), (las_ptr)&Bs[idx * 8], 16, 0, 0);
        }
        if (tid < 256) {
            const int row = tid >> 2, gg = tid & 3;
            const int sg = gg ^ ((row >> 1) & 3);
            __builtin_amdgcn_global_load_lds(
                (gas_ptr)(Ab + (long)row * DMODEL + kt + sg * 8), (las_ptr)&As[tid * 8], 16, 0, 0);
        }
        __syncthreads();
        bf16x8 af[2], bv[8];
#pragma unroll
        for (int m = 0; m < 2; ++m) {
            const int r = wm * 32 + m * 16 + lr;
            af[m] = *(const bf16x8*)&As[r * 32 + (lg ^ ((r >> 1) & 3)) * 8];
        }
#pragma unroll
        for (int n = 0; n < 8; ++n) {
            const int r = wn * 128 + n * 16 + lr;
            bv[n] = *(const bf16x8*)&Bs[r * 32 + (lg ^ ((r >> 1) & 3)) * 8];
        }
#pragma unroll
        for (int m = 0; m < 2; ++m)
#pragma unroll
            for (int n = 0; n < 8; ++n)
                acc[m][n] = __builtin_amdgcn_mfma_f32_16x16x32_bf16(af[m], bv[n], acc[m][n], 0, 0, 0);
        __syncthreads();
    }

    float ps[2][4], pq[2][4];
#pragma unroll
    for (int m = 0; m < 2; ++m)
#pragma unroll
        for (int j = 0; j < 4; ++j) {
            const long r = row0 + wm * 32 + m * 16 + lg * 4 + j;
            const bool valid = r < Mrows;
            float s = 0.f, q = 0.f;
#pragma unroll
            for (int n = 0; n < 8; ++n) {
                float t = acc[m][n][j];
                if (valid) t += res[r * DMODEL + wn * 128 + n * 16 + lr];
                acc[m][n][j] = t;
                s += t; q += t * t;
            }
            ps[m][j] = s; pq[m][j] = q;
        }
#pragma unroll
    for (int o = 1; o < 16; o <<= 1)
#pragma unroll
        for (int m = 0; m < 2; ++m)
#pragma unroll
            for (int j = 0; j < 4; ++j) {
                ps[m][j] += __shfl_xor(ps[m][j], o);
                pq[m][j] += __shfl_xor(pq[m][j], o);
            }
    if (lr == 0) {
#pragma unroll
        for (int m = 0; m < 2; ++m)
#pragma unroll
            for (int j = 0; j < 4; ++j) {
                const int ri = wm * 32 + m * 16 + lg * 4 + j;
                redS[wn][ri] = ps[m][j];
                redQ[wn][ri] = pq[m][j];
            }
    }
    __syncthreads();
    if (tid < 64) {
        const float s = redS[0][tid] + redS[1][tid] + redS[2][tid] + redS[3][tid];
        const float q = redQ[0][tid] + redQ[1][tid] + redQ[2][tid] + redQ[3][tid];
        const float mean = s * (1.f / 512.f);
        const float var = q * (1.f / 512.f) - mean * mean;
        redS[0][tid] = mean;
        redQ[0][tid] = rsqrtf(var + 1e-5f);
    }
    __syncthreads();
#pragma unroll
    for (int m = 0; m < 2; ++m)
#pragma unroll
        for (int j = 0; j < 4; ++j) {
            const int ri = wm * 32 + m * 16 + lg * 4 + j;
            const long r = row0 + ri;
            if (r >= Mrows) continue;
            const float mean = redS[0][ri], rs = redQ[0][ri];
#pragma unroll
            for (int n = 0; n < 8; ++n) {
                const int c = wn * 128 + n * 16 + lr;
                const float o = (acc[m][n][j] - mean) * rs * g[c] + b[c];
                outf[r * DMODEL + c] = o;
                outb[r * DMODEL + c] = __float2bfloat16(o);
            }
        }
}

// ---------------------------------------------------------------------------
// 8-phase GEMM (round-8, refcheck'd). Used for FFN2 (K=2048).
// ---------------------------------------------------------------------------
template<int OUTMODE, bool GELU>
__global__ __launch_bounds__(512, 1)
void gemm8(const u16* __restrict__ A, int lda,
           const u16* __restrict__ Bt, int ldb,
           float* __restrict__ Cf, bf16* __restrict__ Cb, int ldc,
           const float* __restrict__ bias, const float* __restrict__ pos,
           int K, int rows_valid)
{
    __shared__ u16 Ash[2][2][256 * 32];
    __shared__ u16 Bsh[2][2][256 * 32];
    const int tid = threadIdx.x, wid = tid >> 6, lane = tid & 63;
    const int wm = wid >> 2, wn = wid & 3;
    const int lr = lane & 15, lg = lane >> 4;
    const u16* Ab = A + (long)blockIdx.y * 256 * lda;
    const u16* Bb = Bt + (long)blockIdx.x * 256 * ldb;
    const int srow = tid >> 2;
    const int soct = ((tid & 3) ^ (srow & 3)) * 8;
    const int slot8 = (lg ^ (lr & 3)) * 8;

    f32x4 acc[8][4] = {};

    auto stage = [&](u16* dst, const u16* src, int ld, int kt, int kh) {
#pragma unroll
        for (int i = 0; i < 2; ++i)
            __builtin_amdgcn_global_load_lds(
                (gas_ptr)(src + (long)(i * 128 + srow) * ld + kt * 64 + kh * 32 + soct),
                (las_ptr)(dst + (i * 512 + tid) * 8), 16, 0, 0);
    };

#define VMW(n) { asm volatile("s_waitcnt vmcnt(" #n ")" ::: "memory"); \
                 __builtin_amdgcn_sched_barrier(0); }
#define MFMA16(A0)                                                              \
    __builtin_amdgcn_s_setprio(1);                                             \
    _Pragma("unroll")                                                           \
    for (int m = 0; m < 4; ++m)                                                 \
        _Pragma("unroll")                                                       \
        for (int n = 0; n < 4; ++n)                                             \
            acc[(A0) + m][n] = __builtin_amdgcn_mfma_f32_16x16x32_bf16(         \
                af[m], bfr[n], acc[(A0) + m][n], 0, 0, 0);                      \
    __builtin_amdgcn_s_setprio(0);

    const int nt = K / 64;
    stage(&Ash[0][0][0], Ab, lda, 0, 0);
    stage(&Bsh[0][0][0], Bb, ldb, 0, 0);
    stage(&Ash[0][1][0], Ab, lda, 0, 1);
    stage(&Bsh[0][1][0], Bb, ldb, 0, 1);
    VMW(4);
    __builtin_amdgcn_s_barrier();

    for (int t = 0; t < nt; ++t) {
        const int db = t & 1;
        const bool nx = (t + 1 < nt);
        bf16x8 af[4], bfr[4];

#pragma unroll
        for (int n = 0; n < 4; ++n)
            bfr[n] = *(const bf16x8*)&Bsh[db][0][(wn * 64 + n * 16 + lr) * 32 + slot8];
#pragma unroll
        for (int m = 0; m < 4; ++m)
            af[m] = *(const bf16x8*)&Ash[db][0][(wm * 128 + m * 16 + lr) * 32 + slot8];
        if (nx) stage(&Ash[db ^ 1][0][0], Ab, lda, t + 1, 0);
        __builtin_amdgcn_s_barrier();
        MFMA16(0)
        __builtin_amdgcn_s_barrier();

#pragma unroll
        for (int m = 0; m < 4; ++m)
            af[m] = *(const bf16x8*)&Ash[db][0][(wm * 128 + 64 + m * 16 + lr) * 32 + slot8];
        if (nx) { stage(&Bsh[db ^ 1][0][0], Bb, ldb, t + 1, 0); VMW(4); }
        else    { VMW(0); }
        __builtin_amdgcn_s_barrier();
        MFMA16(4)
        __builtin_amdgcn_s_barrier();

#pragma unroll
        for (int n = 0; n < 4; ++n)
            bfr[n] = *(const bf16x8*)&Bsh[db][1][(wn * 64 + n * 16 + lr) * 32 + slot8];
#pragma unroll
        for (int m = 0; m < 4; ++m)
            af[m] = *(const bf16x8*)&Ash[db][1][(wm * 128 + m * 16 + lr) * 32 + slot8];
        if (nx) stage(&Ash[db ^ 1][1][0], Ab, lda, t + 1, 1);
        __builtin_amdgcn_s_barrier();
        MFMA16(0)
        __builtin_amdgcn_s_barrier();

#pragma unroll
        for (int m = 0; m < 4; ++m)
            af[m] = *(const bf16x8*)&Ash[db][1][(wm * 128 + 64 + m * 16 + lr) * 32 + slot8];
        if (nx) { stage(&Bsh[db ^ 1][1][0], Bb, ldb, t + 1, 1); VMW(4); }
        __builtin_amdgcn_s_barrier();
        MFMA16(4)
        __builtin_amdgcn_s_barrier();
    }
#undef MFMA16
#undef VMW

    const int cbase = blockIdx.x * 256 + wn * 64;
    const int rbase = blockIdx.y * 256 + wm * 128;
#pragma unroll
    for (int n = 0; n < 4; ++n) {
        const int c = cbase + n * 16 + lr;
        const float bval = bias ? bias[c] : 0.0f;
#pragma unroll
        for (int a = 0; a < 8; ++a) {
#pragma unroll
            for (int j = 0; j < 4; ++j) {
                const int r = rbase + a * 16 + lg * 4 + j;
                if (r >= rows_valid) continue;
                float v = acc[a][n][j] + bval;
                if constexpr (GELU) v = 0.5f * v * (1.0f + erff(v * 0.70710678118654752f));
                long idx;
                if constexpr (OUTMODE == 1) {
                    const int pb = r / 576, pt = r - pb * 576;
                    v += pos[(long)(1 + pt) * DMODEL + c];
                    idx = (long)(pb * TOKENS + 1 + pt) * ldc + c;
                } else {
                    idx = (long)r * ldc + c;
                }
                if (Cf) Cf[idx] = v;
                if (Cb) Cb[idx] = __float2bfloat16(v);
            }
        }
    }
}

// ---------------------------------------------------------------------------
// Fused flash attention v3 (round-13, kept): kv-tile=64, double-buffered K/V,
// 2-deep counted vmcnt pipeline, wave-private P, XOR-swizzled LDS.
// ---------------------------------------------------------------------------
__global__ __launch_bounds__(256, 2)
void attn_flash(const u16* __restrict__ qkv, const u16* __restrict__ vhT,
                bf16* __restrict__ ob)
{
    __shared__ u16 Ksh[2][64 * 128];
    __shared__ u16 Vsh[2][128 * 64];
    __shared__ u16 Psh[128 * 64];
    const int tid = threadIdx.x;
    const int w = tid >> 6, lane = tid & 63;
    const int lr = lane & 15, lg = lane >> 4;
    const int pair = blockIdx.y;
    const int b = pair >> 2, h = pair & 3;
    const int q0 = blockIdx.x * 128;
    const long rowbase = (long)b * TOKENS;
    const int swrd = lr & 7;

    const u16* kg = qkv + rowbase * 1536 + 512 + h * 128;
    const u16* vg = vhT + (long)pair * 128 * TPAD;

    auto stageK = [&](int buf, int t) {
#pragma unroll
        for (int i = 0; i < 4; ++i) {
            const int slot = i * 256 + tid;
            const int row = slot >> 4, s = slot & 15;
            const int so = (s & 8) | ((s & 7) ^ (row & 7));
            __builtin_amdgcn_global_load_lds(
                (gas_ptr)(kg + (long)(t * 64 + row) * 1536 + so * 8),
                (las_ptr)&Ksh[buf][slot * 8], 16, 0, 0);
        }
    };
    auto stageV = [&](int buf, int t) {
#pragma unroll
        for (int i = 0; i < 4; ++i) {
            const int slot = i * 256 + tid;
            const int row = slot >> 3, s = slot & 7;
            const int so = s ^ (row & 7);
            __builtin_amdgcn_global_load_lds(
                (gas_ptr)(vg + (long)row * TPAD + t * 64 + so * 8),
                (las_ptr)&Vsh[buf][slot * 8], 16, 0, 0);
        }
    };

    bf16x8 qf[2][4];
#pragma unroll
    for (int m = 0; m < 2; ++m)
#pragma unroll
        for (int kf = 0; kf < 4; ++kf) {
            const long r = rowbase + q0 + w * 32 + m * 16 + lr;
            qf[m][kf] = *(const bf16x8*)&qkv[r * 1536 + h * 128 + kf * 32 + lg * 8];
        }

    float mrun[2][4], lrun[2][4];
#pragma unroll
    for (int m = 0; m < 2; ++m)
#pragma unroll
        for (int j = 0; j < 4; ++j) { mrun[m][j] = -1e30f; lrun[m][j] = 0.f; }
    f32x4 oacc[2][8] = {};

    constexpr int NT = TPAD / 64;
    stageK(0, 0); stageV(0, 0);
    stageK(1, 1); stageV(1, 1);
    asm volatile("s_waitcnt vmcnt(8)" ::: "memory");
    __builtin_amdgcn_sched_barrier(0);
    __builtin_amdgcn_s_barrier();

    for (int t = 0; t < NT; ++t) {
        const int cur = t & 1;

        f32x4 s[2][4] = {};
#pragma unroll
        for (int kf = 0; kf < 4; ++kf) {
            const int o = kf * 4 + lg;
            const int so = ((o & 8) | ((o & 7) ^ swrd)) * 8;
            bf16x8 bv[4];
#pragma unroll
            for (int n = 0; n < 4; ++n)
                bv[n] = *(const bf16x8*)&Ksh[cur][(n * 16 + lr) * 128 + so];
            __builtin_amdgcn_s_setprio(1);
#pragma unroll
            for (int m = 0; m < 2; ++m)
#pragma unroll
                for (int n = 0; n < 4; ++n)
                    s[m][n] = __builtin_amdgcn_mfma_f32_16x16x32_bf16(qf[m][kf], bv[n], s[m][n], 0, 0, 0);
            __builtin_amdgcn_s_setprio(0);
        }

        float sc[2][4];
#pragma unroll
        for (int m = 0; m < 2; ++m)
#pragma unroll
            for (int jj = 0; jj < 4; ++jj) {
                float mx = mrun[m][jj];
#pragma unroll
                for (int n = 0; n < 4; ++n) {
                    const int col = t * 64 + n * 16 + lr;
                    float v = s[m][n][jj] * SM_SCALE;
                    v = (col < TOKENS) ? v : -1e30f;
                    s[m][n][jj] = v;
                    mx = fmaxf(mx, v);
                }
#pragma unroll
                for (int o = 1; o < 16; o <<= 1) mx = fmaxf(mx, __shfl_xor(mx, o));
                const float f = __expf(mrun[m][jj] - mx);
                sc[m][jj] = f;
                float sum = 0.f;
#pragma unroll
                for (int n = 0; n < 4; ++n) {
                    const float p = __expf(s[m][n][jj] - mx);
                    s[m][n][jj] = p;
                    sum += p;
                }
#pragma unroll
                for (int o = 1; o < 16; o <<= 1) sum += __shfl_xor(sum, o);
                lrun[m][jj] = lrun[m][jj] * f + sum;
                mrun[m][jj] = mx;
            }
#pragma unroll
        for (int m = 0; m < 2; ++m)
#pragma unroll
            for (int n = 0; n < 8; ++n)
#pragma unroll
                for (int jj = 0; jj < 4; ++jj) oacc[m][n][jj] *= sc[m][jj];

#pragma unroll
        for (int m = 0; m < 2; ++m)
#pragma unroll
            for (int jj = 0; jj < 4; ++jj) {
                const int prow = w * 32 + m * 16 + lg * 4 + jj;
                const int p7 = prow & 7;
#pragma unroll
                for (int n = 0; n < 4; ++n) {
                    const int c = n * 16 + lr;
                    Psh[prow * 64 + (((c >> 3) ^ p7) << 3) + (c & 7)] = f2b(s[m][n][jj]);
                }
            }

#pragma unroll
        for (int kf = 0; kf < 2; ++kf) {
            const int so = ((kf * 4 + lg) ^ swrd) * 8;
            bf16x8 pa[2];
#pragma unroll
            for (int m = 0; m < 2; ++m)
                pa[m] = *(const bf16x8*)&Psh[(w * 32 + m * 16 + lr) * 64 + so];
            __builtin_amdgcn_s_setprio(1);
#pragma unroll
            for (int n = 0; n < 8; ++n) {
                const bf16x8 vb = *(const bf16x8*)&Vsh[cur][(n * 16 + lr) * 64 + so];
#pragma unroll
                for (int m = 0; m < 2; ++m)
                    oacc[m][n] = __builtin_amdgcn_mfma_f32_16x16x32_bf16(pa[m], vb, oacc[m][n], 0, 0, 0);
            }
            __builtin_amdgcn_s_setprio(0);
        }

        __builtin_amdgcn_s_barrier();
        if (t + 2 < NT) { stageK(cur, t + 2); stageV(cur, t + 2); }
        if (t + 1 < NT) {
            if (t + 2 < NT) { asm volatile("s_waitcnt vmcnt(8)" ::: "memory"); }
            else            { asm volatile("s_waitcnt vmcnt(0)" ::: "memory"); }
            __builtin_amdgcn_sched_barrier(0);
        }
        __builtin_amdgcn_s_barrier();
    }

#pragma unroll
    for (int m = 0; m < 2; ++m)
#pragma unroll
        for (int jj = 0; jj < 4; ++jj) {
            const float inv = 1.f / lrun[m][jj];
            const int q = q0 + w * 32 + m * 16 + lg * 4 + jj;
            if (q >= TOKENS) continue;
#pragma unroll
            for (int n = 0; n < 8; ++n)
                ob[(rowbase + q) * DMODEL + h * 128 + n * 16 + lr] =
                    __float2bfloat16(oacc[m][n][jj] * inv);
        }
}

// ---------------------------------------------------------------------------
// Patch-embed weight transpose (once).
// ---------------------------------------------------------------------------
__global__ __launch_bounds__(256)
void wtrans(const float* __restrict__ W, bf16* __restrict__ WT, int K, int N)
{
    __shared__ float tile[32][33];
    const int n0 = blockIdx.x * 32, k0 = blockIdx.y * 32;
    const int tx = threadIdx.x & 31, ty = threadIdx.x >> 5;
#pragma unroll
    for (int i = 0; i < 4; ++i)
        tile[ty + i * 8][tx] = W[(long)(k0 + ty + i * 8) * N + n0 + tx];
    __syncthreads();
#pragma unroll
    for (int i = 0; i < 4; ++i)
        WT[(long)(n0 + ty + i * 8) * K + k0 + tx] = __float2bfloat16(tile[tx][ty + i * 8]);
}

// ---------------------------------------------------------------------------
// Layer weight transpose. w2T now k-permuted within 64-blocks to match FFN1's
// packed (column-interleaved) h1b layout: kphys = (s&15)*4 + (s>>4).
// ---------------------------------------------------------------------------
__global__ __launch_bounds__(256)
void wtrans_layers(const float* __restrict__ Wqkv, const float* __restrict__ W0,
                   const float* __restrict__ W1, const float* __restrict__ W2,
                   bf16* __restrict__ out, int layer0)
{
    const int bb = blockIdx.x;
    const int sl = bb / 3072;
    const int l = layer0 + sl;
    int t = bb % 3072;
    bf16* base = out + (long)sl * LAYER_W;
    const float* W; bf16* WT; int K, N; int mode = 0;   // 1=qkv perm, 2=w2 kperm
    if (t < 768)       {            W = Wqkv + (long)l * 512 * 1536; WT = base;           K = 512;  N = 1536; mode = 1; }
    else if (t < 1024) { t -= 768;  W = W0   + (long)l * 512 * 512;  WT = base + 786432;  K = 512;  N = 512;  }
    else if (t < 2048) { t -= 1024; W = W1   + (long)l * 512 * 2048; WT = base + 1048576; K = 512;  N = 2048; }
    else               { t -= 2048; W = W2   + (long)l * 2048 * 512; WT = base + 2097152; K = 2048; N = 512;  mode = 2; }
    const int nx = N / 32;
    const int n0 = (t % nx) * 32, k0 = (t / nx) * 32;
    __shared__ float tile[32][33];
    const int tx = threadIdx.x & 31, ty = threadIdx.x >> 5;
#pragma unroll
    for (int i = 0; i < 4; ++i)
        tile[ty + i * 8][tx] = W[(long)(k0 + ty + i * 8) * N + n0 + tx];
    __syncthreads();
#pragma unroll
    for (int i = 0; i < 4; ++i) {
        int n = n0 + ty + i * 8;
        if (mode == 1) {
            const int d = n / 12, rr = n % 12;
            n = (rr >> 2) * 512 + (rr & 3) * 128 + d;
        }
        int kk = k0 + tx;
        if (mode == 2) {
            const int s = kk & 63;
            kk = (kk & ~63) | (((s & 15) << 2) | (s >> 4));
        }
        WT[(long)n * K + kk] = __float2bfloat16(tile[tx][ty + i * 8]);
    }
}

// ---------------------------------------------------------------------------
__global__ __launch_bounds__(64)
void patch_gather(const float* __restrict__ img, bf16* __restrict__ pat)
{
    const int bid = blockIdx.x;
    const int x  = bid % 24;
    const int p1 = (bid / 24) % 16;
    const int b  = bid / (24 * 16);
    __shared__ bf16 lds[24][48];
    const int lane = threadIdx.x;
    const int h = p1 * 24 + x;
    for (int c = 0; c < 3; ++c) {
        const float* row = img + ((long)(b * 3 + c) * 384 + h) * 384;
#pragma unroll
        for (int i = 0; i < 6; ++i) {
            const int wpix = lane + i * 64;
            const float v = row[wpix];
            const int y = wpix % 24, p2 = wpix / 24;
            lds[y][p2 * 3 + c] = __float2bfloat16(v);
        }
    }
    __syncthreads();
    for (int idx = lane; idx < 24 * 48; idx += 64) {
        const int y = idx / 48, j = idx % 48;
        pat[(long)(b * 576 + x * 24 + y) * 768 + p1 * 48 + j] = lds[y][j];
    }
}

__global__ __launch_bounds__(256)
void clsfill(const float* __restrict__ cls, const float* __restrict__ pos,
             float* __restrict__ tokf, bf16* __restrict__ xb)
{
    const int i = blockIdx.x * 256 + threadIdx.x;
    const int b = i >> 9, d = i & 511;
    const float v = cls[d] + pos[d];
    tokf[(long)b * TOKENS * DMODEL + d] = v;
    xb[(long)b * TOKENS * DMODEL + d] = __float2bfloat16(v);
}

__global__ __launch_bounds__(256)
void repack_v(const u16* __restrict__ qkv, u16* __restrict__ vhT)
{
    __shared__ u16 lds[64][136];
    const int bid = blockIdx.x;
    const int tt = bid % 10, pair = bid / 10;
    const int b = pair >> 2, h = pair & 3;
    const int tid = threadIdx.x;
    const int tl = tid >> 2, seg = tid & 3;
    const long row = (long)b * TOKENS + tt * 64 + tl;
    const u16* src = qkv + row * 1536 + 1024 + h * 128 + seg * 32;
#pragma unroll
    for (int u = 0; u < 4; ++u)
        *(uint4*)&lds[tl][seg * 32 + u * 8] = *(const uint4*)&src[u * 8];
    __syncthreads();
    const int d = tid >> 1, th = (tid & 1) * 32;
    u16* dst = vhT + ((long)pair * 128 + d) * TPAD + tt * 64 + th;
#pragma unroll
    for (int blk = 0; blk < 4; ++blk) {
        uint4 pk; u16* pp = (u16*)&pk;
#pragma unroll
        for (int j = 0; j < 8; ++j) {
            const int t = tt * 64 + th + blk * 8 + j;
            pp[j] = (t < TOKENS) ? lds[th + blk * 8 + j][d] : (u16)0;
        }
        *(uint4*)&dst[blk * 8] = pk;
    }
}

// y = LN(xin + res)*g + b  (LN2)
__global__ __launch_bounds__(256)
void resln(const float* __restrict__ xin, const float* __restrict__ res,
           const float* __restrict__ g, const float* __restrict__ b,
           float* __restrict__ outf, bf16* __restrict__ outb, int nrows)
{
    const int row = blockIdx.x * 4 + (threadIdx.x >> 6);
    if (row >= nrows) return;
    const int lane = threadIdx.x & 63;
    const float* p1 = xin + (long)row * DMODEL;
    const float* p2 = res + (long)row * DMODEL;
    float v[8];
    float s = 0.f;
#pragma unroll
    for (int i = 0; i < 8; ++i) { v[i] = p1[lane + i * 64] + p2[lane + i * 64]; s += v[i]; }
#pragma unroll
    for (int o = 32; o; o >>= 1) s += __shfl_xor(s, o);
    const float mean = s * (1.f / 512.f);
    float q = 0.f;
#pragma unroll
    for (int i = 0; i < 8; ++i) { const float d = v[i] - mean; q += d * d; }
#pragma unroll
    for (int o = 32; o; o >>= 1) q += __shfl_xor(q, o);
    const float rs = rsqrtf(q * (1.f / 512.f) + 1e-5f);
#pragma unroll
    for (int i = 0; i < 8; ++i) {
        const int c = lane + i * 64;
        const float o = (v[i] - mean) * rs * g[c] + b[c];
        outf[(long)row * DMODEL + c] = o;
        outb[(long)row * DMODEL + c] = __float2bfloat16(o);
    }
}

__global__ __launch_bounds__(64)
void head_k(const float* __restrict__ tokf, const float* __restrict__ Wh,
            const float* __restrict__ bh, float* __restrict__ out)
{
    const int b = blockIdx.x;
    const int lane = threadIdx.x;
    const float* x = tokf + (long)b * TOKENS * DMODEL;
    float acc[10] = {};
#pragma unroll
    for (int i = 0; i < 8; ++i) {
        const int d = lane + i * 64;
        const float xv = x[d];
        const float* wr = Wh + (long)d * 10;
#pragma unroll
        for (int c = 0; c < 10; ++c) acc[c] += xv * wr[c];
    }
#pragma unroll
    for (int c = 0; c < 10; ++c)
#pragma unroll
        for (int o = 32; o; o >>= 1) acc[c] += __shfl_xor(acc[c], o);
    if (lane == 0) {
#pragma unroll
        for (int c = 0; c < 10; ++c) out[b * 10 + c] = acc[c] + bh[c];
    }
}

// ---------------------------------------------------------------------------
extern "C" void kernel_launch(void* const* d_in, const int* in_sizes, int n_in,
                              void* d_out, int out_size, void* d_ws, size_t ws_size,
                              hipStream_t stream)
{
    (void)in_sizes; (void)n_in; (void)out_size;
    const float* img    = (const float*)d_in[0];
    const float* Wpatch = (const float*)d_in[1];
    const float* bpatch = (const float*)d_in[2];
    const float* clstk  = (const float*)d_in[3];
    const float* pos    = (const float*)d_in[4];
    const float* Wqkv   = (const float*)d_in[5];
    const float* W0     = (const float*)d_in[6];
    const float* g1     = (const float*)d_in[7];
    const float* b1     = (const float*)d_in[8];
    const float* g2     = (const float*)d_in[9];
    const float* b2     = (const float*)d_in[10];
    const float* W1     = (const float*)d_in[11];
    const float* bb1    = (const float*)d_in[12];
    const float* W2     = (const float*)d_in[13];
    const float* bb2    = (const float*)d_in[14];
    const float* Whead  = (const float*)d_in[15];
    const float* bhead  = (const float*)d_in[16];

    // ---- config ladder: (batch chunk, weight buffers) ----
    static const int cand[7][2] = {{32,6},{32,1},{16,1},{8,1},{4,1},{2,1},{1,1}};
    int Bc = 0, nW = 1;
    size_t o_tokf=0, o_xb=0, o_R1=0, o_R2=0, o_ob=0, o_wp=0, o_wr=0;
    for (int ci = 0; ci < 7; ++ci) {
        const int bc = cand[ci][0], nw = cand[ci][1];
        const long Mrows = (long)bc * TOKENS;
        const long Mpad  = ((Mrows + 255) / 256) * 256;
        size_t off = 0;
        auto take = [&](size_t sz) { size_t o = off; off += (sz + 255) & ~(size_t)255; return o; };
        size_t t_tokf = take((size_t)Mpad * 512 * 4);
        size_t t_xb   = take((size_t)Mpad * 512 * 2);
        size_t t_R1   = take((size_t)Mpad * 2048 * 2);          // pat | qkv | h1b
        size_t r2a = (size_t)bc * 4 * TPAD * 128 * 2;           // vhT
        size_t r2b = (size_t)Mpad * 512 * 4;                    // t1 (f32)
        size_t t_R2 = take(r2a > r2b ? r2a : r2b);
        size_t t_ob   = take((size_t)Mpad * 512 * 2);
        size_t t_wp   = take((size_t)512 * 768 * 2);
        size_t t_wr   = take((size_t)nw * LAYER_W * 2);
        if (off <= ws_size) {
            Bc = bc; nW = nw;
            o_tokf=t_tokf; o_xb=t_xb; o_R1=t_R1; o_R2=t_R2; o_ob=t_ob; o_wp=t_wp; o_wr=t_wr;
            break;
        }
    }
    if (Bc == 0) return;

    const long Mrows = (long)Bc * TOKENS;
    const long Mpad  = ((Mrows + 255) / 256) * 256;
    const int  NP    = Bc * 4;
    const int  gy128 = (int)(Mpad / 128);
    const int  gy256 = (int)(Mpad / 256);
    const int  nproj = (int)((Mrows + 63) / 64);
    const long patRows = ((long)Bc * 576 + 127) / 128 * 128;

    char* base = (char*)d_ws;
    float* tokf = (float*)(base + o_tokf);
    bf16*  xb   = (bf16*)(base + o_xb);
    char*  R1   = base + o_R1;
    char*  R2   = base + o_R2;
    bf16*  ob   = (bf16*)(base + o_ob);
    bf16*  wpT  = (bf16*)(base + o_wp);
    bf16*  wAll = (bf16*)(base + o_wr);

    u16*  qkvb = (u16*)R1;
    bf16* pat  = (bf16*)R1;
    u16*  h1b  = (u16*)R1;
    u16*  vhT  = (u16*)R2;
    float* t1  = (float*)R2;

    wtrans<<<dim3(512 / 32, 768 / 32), 256, 0, stream>>>(Wpatch, wpT, 768, 512);
    if (nW == 6)
        wtrans_layers<<<6 * 3072, 256, 0, stream>>>(Wqkv, W0, W1, W2, wAll, 0);

    const int nchunks = 32 / Bc;
    for (int ch = 0; ch < nchunks; ++ch) {
        const float* img_c = img + (long)ch * Bc * 3 * 384 * 384;

        hipMemsetAsync(xb, 0, (size_t)Mpad * 512 * 2, stream);   // pad rows -> exact 0
        clsfill<<<Bc * 2, 256, 0, stream>>>(clstk, pos, tokf, xb);
        patch_gather<<<Bc * 16 * 24, 64, 0, stream>>>(img_c, pat);
        gemm_bt<1, false><<<dim3(4, (int)(patRows / 128)), 256, 0, stream>>>(
            (const u16*)pat, 768, (const u16*)wpT, 768,
            tokf, xb, 512, bpatch, pos, 768, Bc * 576);

        for (int l = 0; l < 6; ++l) {
            const bf16* wL = wAll + (nW == 6 ? (long)l * LAYER_W : 0);
            if (nW == 1)
                wtrans_layers<<<3072, 256, 0, stream>>>(Wqkv, W0, W1, W2, wAll, l);
            const u16* wqkvT = (const u16*)wL;
            const u16* w0T   = (const u16*)(wL + 786432);
            const u16* w1T   = (const u16*)(wL + 1048576);
            const u16* w2T   = (const u16*)(wL + 2097152);

            // qkv = x @ Wqkv  (BK=32 kernel; logical layout, unpacked)
            gemm_bt32<false, false><<<dim3(12, gy128), 256, 0, stream>>>(
                (const u16*)xb, 512, wqkvT, 512,
                (bf16*)qkvb, 1536, nullptr, 512, (int)Mpad);

            repack_v<<<NP * 10, 256, 0, stream>>>(qkvb, vhT);
            attn_flash<<<dim3(5, NP), 256, 0, stream>>>(qkvb, vhT, ob);

            // fused proj + residual + LN1 -> tokf, xb
            proj_ln<<<nproj, 512, 0, stream>>>(
                (const u16*)ob, w0T, tokf, g1 + l * 512, b1 + l * 512,
                tokf, xb, (int)Mrows);

            // h1 = gelu(y @ W1 + bb1), packed interleaved stores
            gemm_bt32<true, true><<<dim3(16, gy128), 256, 0, stream>>>(
                (const u16*)xb, 512, w1T, 512,
                (bf16*)h1b, 2048, bb1 + l * 2048, 512, (int)Mrows);

            // t1 = h1 @ W2 + bb2  (w2T k-permuted to match packed h1b)
            gemm8<0, false><<<dim3(2, gy256), 512, 0, stream>>>(
                (const u16*)h1b, 2048, w2T, 2048,
                t1, nullptr, 512, bb2 + l * 512, nullptr, 2048, (int)Mrows);
            // x = LN(t1 + y) -> tokf, xb
            resln<<<(int)((Mrows + 3) / 4), 256, 0, stream>>>(
                t1, tokf, g2 + l * 512, b2 + l * 512, tokf, xb, (int)Mrows);
        }

        head_k<<<Bc, 64, 0, stream>>>(tokf, Whead, bhead, (float*)d_out + (long)ch * Bc * 10);
    }
}

// Round 15
// 2447.926 us; speedup vs baseline: 1.4599x; 1.0809x over previous
//
#include <hip/hip_runtime.h>
#include <hip/hip_bf16.h>

// ViT forward, MI355X. All big GEMMs on the BK=32 swizzled kernel; qkv AND
// FFN1 use packed interleaved stores (consumers compensated: w0T/w2T
// k-permuted with the verified Phi map); FFN2 outputs bf16; pipelined flash
// attention; proj+residual+LN fused.

typedef unsigned short u16;
typedef __hip_bfloat16 bf16;
typedef __bf16 bf16x8 __attribute__((ext_vector_type(8)));
typedef float f32x4 __attribute__((ext_vector_type(4)));

typedef const __attribute__((address_space(1))) void* gas_ptr;
typedef __attribute__((address_space(3))) void* las_ptr;

#define TOKENS 577
#define TPAD   640
#define DMODEL 512
#define SM_SCALE 0.08838834764831845f   /* 128^-0.5 */
#define LAYER_W 3145728l                /* bf16 elems per layer's weights */

static __device__ __forceinline__ u16 f2b(float v) {
    bf16 t = __float2bfloat16(v);
    return *(u16*)&t;
}

// ---------------------------------------------------------------------------
// BK=32 GEMM, 128x128 tile, swizzled LDS, measured-best block-step throughput.
// OMODE 0: plain bf16 out. 1: packed bf16 (phys col = cbase + lr*4 + n;
// consumers compensated via k-perm Phi(k)=(k&15)*4+(k>>4) per 64-block).
// 3: patch-embed (row remap b*577+1+t, +bias+pos, f32 tokf + bf16 xb).
// ---------------------------------------------------------------------------
template<bool GELU, int OMODE>
__global__ __launch_bounds__(256)
void gemm_bt32(const u16* __restrict__ A, int lda,
               const u16* __restrict__ Bt, int ldb,
               bf16* __restrict__ Cb, float* __restrict__ Cf, int ldc,
               const float* __restrict__ bias, const float* __restrict__ pos,
               int K, int rows_valid)
{
    __shared__ u16 As[128 * 32];
    __shared__ u16 Bs[128 * 32];
    const int tid  = threadIdx.x;
    const int w    = tid >> 6;
    const int lane = tid & 63;
    const u16* Ab = A + (long)blockIdx.y * 128 * lda;
    const u16* Bb = Bt + (long)blockIdx.x * 128 * ldb;
    const int wr = w >> 1, wc = w & 1;
    const int lr = lane & 15, lg = lane >> 4;
    f32x4 acc[4][4] = {};

    for (int kt = 0; kt < K; kt += 32) {
#pragma unroll
        for (int rd = 0; rd < 2; ++rd) {
            const int idx = rd * 256 + tid;
            const int row = idx >> 2, g = idx & 3;
            const int sg = g ^ ((row >> 1) & 3);
            __builtin_amdgcn_global_load_lds(
                (gas_ptr)(Ab + (long)row * lda + kt + sg * 8), (las_ptr)&As[idx * 8], 16, 0, 0);
            __builtin_amdgcn_global_load_lds(
                (gas_ptr)(Bb + (long)row * ldb + kt + sg * 8), (las_ptr)&Bs[idx * 8], 16, 0, 0);
        }
        __syncthreads();
        bf16x8 af[4], bv[4];
#pragma unroll
        for (int m = 0; m < 4; ++m) {
            const int r = wr * 64 + m * 16 + lr;
            af[m] = *(const bf16x8*)&As[r * 32 + (lg ^ ((r >> 1) & 3)) * 8];
        }
#pragma unroll
        for (int n = 0; n < 4; ++n) {
            const int r = wc * 64 + n * 16 + lr;
            bv[n] = *(const bf16x8*)&Bs[r * 32 + (lg ^ ((r >> 1) & 3)) * 8];
        }
#pragma unroll
        for (int m = 0; m < 4; ++m)
#pragma unroll
            for (int n = 0; n < 4; ++n)
                acc[m][n] = __builtin_amdgcn_mfma_f32_16x16x32_bf16(af[m], bv[n], acc[m][n], 0, 0, 0);
        __syncthreads();
    }

    const int cbase = blockIdx.x * 128 + wc * 64;
    const int rbase = blockIdx.y * 128 + wr * 64;
    float bval[4];
#pragma unroll
    for (int n = 0; n < 4; ++n) bval[n] = bias ? bias[cbase + n * 16 + lr] : 0.0f;

    if constexpr (OMODE == 1) {
#pragma unroll
        for (int m = 0; m < 4; ++m) {
#pragma unroll
            for (int j = 0; j < 4; ++j) {
                const int r = rbase + m * 16 + lg * 4 + j;
                if (r >= rows_valid) continue;
                u16 pk[4];
#pragma unroll
                for (int n = 0; n < 4; ++n) {
                    float v = acc[m][n][j] + bval[n];
                    if constexpr (GELU) v = 0.5f * v * (1.0f + erff(v * 0.70710678118654752f));
                    pk[n] = f2b(v);
                }
                *(uint2*)&Cb[(long)r * ldc + cbase + lr * 4] = *(uint2*)pk;
            }
        }
    } else if constexpr (OMODE == 3) {
#pragma unroll
        for (int m = 0; m < 4; ++m) {
#pragma unroll
            for (int j = 0; j < 4; ++j) {
                const int r = rbase + m * 16 + lg * 4 + j;
                if (r >= rows_valid) continue;
                const int pb = r / 576, pt = r - pb * 576;
                const long orow = (long)pb * TOKENS + 1 + pt;
#pragma unroll
                for (int n = 0; n < 4; ++n) {
                    const int c = cbase + n * 16 + lr;
                    const float v = acc[m][n][j] + bval[n] + pos[(long)(1 + pt) * DMODEL + c];
                    Cf[orow * ldc + c] = v;
                    Cb[orow * ldc + c] = __float2bfloat16(v);
                }
            }
        }
    } else {
#pragma unroll
        for (int n = 0; n < 4; ++n) {
            const int c = cbase + n * 16 + lr;
#pragma unroll
            for (int m = 0; m < 4; ++m) {
#pragma unroll
                for (int j = 0; j < 4; ++j) {
                    const int r = rbase + m * 16 + lg * 4 + j;
                    if (r >= rows_valid) continue;
                    float v = acc[m][n][j] + bval[n];
                    if constexpr (GELU) v = 0.5f * v * (1.0f + erff(v * 0.70710678118654752f));
                    Cb[(long)r * ldc + c] = __float2bfloat16(v);
                }
            }
        }
    }
}

// ---------------------------------------------------------------------------
// Fused proj + residual + LayerNorm (round-11, kept; w0T k-permuted to match
// packed ob layout — contraction pairs physical k on both sides).
// ---------------------------------------------------------------------------
__global__ __launch_bounds__(512)
void proj_ln(const u16* __restrict__ A, const u16* __restrict__ Bt,
             const float* __restrict__ res,
             const float* __restrict__ g, const float* __restrict__ b,
             float* __restrict__ outf, bf16* __restrict__ outb, int Mrows)
{
    __shared__ u16 As[64 * 32];
    __shared__ u16 Bs[512 * 32];
    __shared__ float redS[4][64];
    __shared__ float redQ[4][64];
    const int tid = threadIdx.x, wid = tid >> 6, lane = tid & 63;
    const int wm = wid >> 2, wn = wid & 3;
    const int lr = lane & 15, lg = lane >> 4;
    const long row0 = (long)blockIdx.x * 64;
    const u16* Ab = A + row0 * DMODEL;
    f32x4 acc[2][8] = {};

    for (int kt = 0; kt < 512; kt += 32) {
#pragma unroll
        for (int rd = 0; rd < 4; ++rd) {
            const int idx = rd * 512 + tid;
            const int row = idx >> 2, gg = idx & 3;
            const int sg = gg ^ ((row >> 1) & 3);
            __builtin_amdgcn_global_load_lds(
                (gas_ptr)(Bt + (long)row * DMODEL + kt + sg * 8), (las_ptr)&Bs[idx * 8], 16, 0, 0);
        }
        if (tid < 256) {
            const int row = tid >> 2, gg = tid & 3;
            const int sg = gg ^ ((row >> 1) & 3);
            __builtin_amdgcn_global_load_lds(
                (gas_ptr)(Ab + (long)row * DMODEL + kt + sg * 8), (las_ptr)&As[tid * 8], 16, 0, 0);
        }
        __syncthreads();
        bf16x8 af[2], bv[8];
#pragma unroll
        for (int m = 0; m < 2; ++m) {
            const int r = wm * 32 + m * 16 + lr;
            af[m] = *(const bf16x8*)&As[r * 32 + (lg ^ ((r >> 1) & 3)) * 8];
        }
#pragma unroll
        for (int n = 0; n < 8; ++n) {
            const int r = wn * 128 + n * 16 + lr;
            bv[n] = *(const bf16x8*)&Bs[r * 32 + (lg ^ ((r >> 1) & 3)) * 8];
        }
#pragma unroll
        for (int m = 0; m < 2; ++m)
#pragma unroll
            for (int n = 0; n < 8; ++n)
                acc[m][n] = __builtin_amdgcn_mfma_f32_16x16x32_bf16(af[m], bv[n], acc[m][n], 0, 0, 0);
        __syncthreads();
    }

    float ps[2][4], pq[2][4];
#pragma unroll
    for (int m = 0; m < 2; ++m)
#pragma unroll
        for (int j = 0; j < 4; ++j) {
            const long r = row0 + wm * 32 + m * 16 + lg * 4 + j;
            const bool valid = r < Mrows;
            float s = 0.f, q = 0.f;
#pragma unroll
            for (int n = 0; n < 8; ++n) {
                float t = acc[m][n][j];
                if (valid) t += res[r * DMODEL + wn * 128 + n * 16 + lr];
                acc[m][n][j] = t;
                s += t; q += t * t;
            }
            ps[m][j] = s; pq[m][j] = q;
        }
#pragma unroll
    for (int o = 1; o < 16; o <<= 1)
#pragma unroll
        for (int m = 0; m < 2; ++m)
#pragma unroll
            for (int j = 0; j < 4; ++j) {
                ps[m][j] += __shfl_xor(ps[m][j], o);
                pq[m][j] += __shfl_xor(pq[m][j], o);
            }
    if (lr == 0) {
#pragma unroll
        for (int m = 0; m < 2; ++m)
#pragma unroll
            for (int j = 0; j < 4; ++j) {
                const int ri = wm * 32 + m * 16 + lg * 4 + j;
                redS[wn][ri] = ps[m][j];
                redQ[wn][ri] = pq[m][j];
            }
    }
    __syncthreads();
    if (tid < 64) {
        const float s = redS[0][tid] + redS[1][tid] + redS[2][tid] + redS[3][tid];
        const float q = redQ[0][tid] + redQ[1][tid] + redQ[2][tid] + redQ[3][tid];
        const float mean = s * (1.f / 512.f);
        const float var = q * (1.f / 512.f) - mean * mean;
        redS[0][tid] = mean;
        redQ[0][tid] = rsqrtf(var + 1e-5f);
    }
    __syncthreads();
#pragma unroll
    for (int m = 0; m < 2; ++m)
#pragma unroll
        for (int j = 0; j < 4; ++j) {
            const int ri = wm * 32 + m * 16 + lg * 4 + j;
            const long r = row0 + ri;
            if (r >= Mrows) continue;
            const float mean = redS[0][ri], rs = redQ[0][ri];
#pragma unroll
            for (int n = 0; n < 8; ++n) {
                const int c = wn * 128 + n * 16 + lr;
                const float o = (acc[m][n][j] - mean) * rs * g[c] + b[c];
                outf[r * DMODEL + c] = o;
                outb[r * DMODEL + c] = __float2bfloat16(o);
            }
        }
}

// ---------------------------------------------------------------------------
// Fused flash attention v3 (round-13, kept): kv-tile=64, double-buffered K/V,
// 2-deep counted vmcnt pipeline, wave-private P, XOR-swizzled LDS.
// ---------------------------------------------------------------------------
__global__ __launch_bounds__(256, 2)
void attn_flash(const u16* __restrict__ qkv, const u16* __restrict__ vhT,
                bf16* __restrict__ ob)
{
    __shared__ u16 Ksh[2][64 * 128];
    __shared__ u16 Vsh[2][128 * 64];
    __shared__ u16 Psh[128 * 64];
    const int tid = threadIdx.x;
    const int w = tid >> 6, lane = tid & 63;
    const int lr = lane & 15, lg = lane >> 4;
    const int pair = blockIdx.y;
    const int b = pair >> 2, h = pair & 3;
    const int q0 = blockIdx.x * 128;
    const long rowbase = (long)b * TOKENS;
    const int swrd = lr & 7;

    const u16* kg = qkv + rowbase * 1536 + 512 + h * 128;
    const u16* vg = vhT + (long)pair * 128 * TPAD;

    auto stageK = [&](int buf, int t) {
#pragma unroll
        for (int i = 0; i < 4; ++i) {
            const int slot = i * 256 + tid;
            const int row = slot >> 4, s = slot & 15;
            const int so = (s & 8) | ((s & 7) ^ (row & 7));
            __builtin_amdgcn_global_load_lds(
                (gas_ptr)(kg + (long)(t * 64 + row) * 1536 + so * 8),
                (las_ptr)&Ksh[buf][slot * 8], 16, 0, 0);
        }
    };
    auto stageV = [&](int buf, int t) {
#pragma unroll
        for (int i = 0; i < 4; ++i) {
            const int slot = i * 256 + tid;
            const int row = slot >> 3, s = slot & 7;
            const int so = s ^ (row & 7);
            __builtin_amdgcn_global_load_lds(
                (gas_ptr)(vg + (long)row * TPAD + t * 64 + so * 8),
                (las_ptr)&Vsh[buf][slot * 8], 16, 0, 0);
        }
    };

    bf16x8 qf[2][4];
#pragma unroll
    for (int m = 0; m < 2; ++m)
#pragma unroll
        for (int kf = 0; kf < 4; ++kf) {
            const long r = rowbase + q0 + w * 32 + m * 16 + lr;
            qf[m][kf] = *(const bf16x8*)&qkv[r * 1536 + h * 128 + kf * 32 + lg * 8];
        }

    float mrun[2][4], lrun[2][4];
#pragma unroll
    for (int m = 0; m < 2; ++m)
#pragma unroll
        for (int j = 0; j < 4; ++j) { mrun[m][j] = -1e30f; lrun[m][j] = 0.f; }
    f32x4 oacc[2][8] = {};

    constexpr int NT = TPAD / 64;
    stageK(0, 0); stageV(0, 0);
    stageK(1, 1); stageV(1, 1);
    asm volatile("s_waitcnt vmcnt(8)" ::: "memory");
    __builtin_amdgcn_sched_barrier(0);
    __builtin_amdgcn_s_barrier();

    for (int t = 0; t < NT; ++t) {
        const int cur = t & 1;

        f32x4 s[2][4] = {};
#pragma unroll
        for (int kf = 0; kf < 4; ++kf) {
            const int o = kf * 4 + lg;
            const int so = ((o & 8) | ((o & 7) ^ swrd)) * 8;
            bf16x8 bv[4];
#pragma unroll
            for (int n = 0; n < 4; ++n)
                bv[n] = *(const bf16x8*)&Ksh[cur][(n * 16 + lr) * 128 + so];
            __builtin_amdgcn_s_setprio(1);
#pragma unroll
            for (int m = 0; m < 2; ++m)
#pragma unroll
                for (int n = 0; n < 4; ++n)
                    s[m][n] = __builtin_amdgcn_mfma_f32_16x16x32_bf16(qf[m][kf], bv[n], s[m][n], 0, 0, 0);
            __builtin_amdgcn_s_setprio(0);
        }

        float sc[2][4];
#pragma unroll
        for (int m = 0; m < 2; ++m)
#pragma unroll
            for (int jj = 0; jj < 4; ++jj) {
                float mx = mrun[m][jj];
#pragma unroll
                for (int n = 0; n < 4; ++n) {
                    const int col = t * 64 + n * 16 + lr;
                    float v = s[m][n][jj] * SM_SCALE;
                    v = (col < TOKENS) ? v : -1e30f;
                    s[m][n][jj] = v;
                    mx = fmaxf(mx, v);
                }
#pragma unroll
                for (int o = 1; o < 16; o <<= 1) mx = fmaxf(mx, __shfl_xor(mx, o));
                const float f = __expf(mrun[m][jj] - mx);
                sc[m][jj] = f;
                float sum = 0.f;
#pragma unroll
                for (int n = 0; n < 4; ++n) {
                    const float p = __expf(s[m][n][jj] - mx);
                    s[m][n][jj] = p;
                    sum += p;
                }
#pragma unroll
                for (int o = 1; o < 16; o <<= 1) sum += __shfl_xor(sum, o);
                lrun[m][jj] = lrun[m][jj] * f + sum;
                mrun[m][jj] = mx;
            }
#pragma unroll
        for (int m = 0; m < 2; ++m)
#pragma unroll
            for (int n = 0; n < 8; ++n)
#pragma unroll
                for (int jj = 0; jj < 4; ++jj) oacc[m][n][jj] *= sc[m][jj];

#pragma unroll
        for (int m = 0; m < 2; ++m)
#pragma unroll
            for (int jj = 0; jj < 4; ++jj) {
                const int prow = w * 32 + m * 16 + lg * 4 + jj;
                const int p7 = prow & 7;
#pragma unroll
                for (int n = 0; n < 4; ++n) {
                    const int c = n * 16 + lr;
                    Psh[prow * 64 + (((c >> 3) ^ p7) << 3) + (c & 7)] = f2b(s[m][n][jj]);
                }
            }

#pragma unroll
        for (int kf = 0; kf < 2; ++kf) {
            const int so = ((kf * 4 + lg) ^ swrd) * 8;
            bf16x8 pa[2];
#pragma unroll
            for (int m = 0; m < 2; ++m)
                pa[m] = *(const bf16x8*)&Psh[(w * 32 + m * 16 + lr) * 64 + so];
            __builtin_amdgcn_s_setprio(1);
#pragma unroll
            for (int n = 0; n < 8; ++n) {
                const bf16x8 vb = *(const bf16x8*)&Vsh[cur][(n * 16 + lr) * 64 + so];
#pragma unroll
                for (int m = 0; m < 2; ++m)
                    oacc[m][n] = __builtin_amdgcn_mfma_f32_16x16x32_bf16(pa[m], vb, oacc[m][n], 0, 0, 0);
            }
            __builtin_amdgcn_s_setprio(0);
        }

        __builtin_amdgcn_s_barrier();
        if (t + 2 < NT) { stageK(cur, t + 2); stageV(cur, t + 2); }
        if (t + 1 < NT) {
            if (t + 2 < NT) { asm volatile("s_waitcnt vmcnt(8)" ::: "memory"); }
            else            { asm volatile("s_waitcnt vmcnt(0)" ::: "memory"); }
            __builtin_amdgcn_sched_barrier(0);
        }
        __builtin_amdgcn_s_barrier();
    }

#pragma unroll
    for (int m = 0; m < 2; ++m)
#pragma unroll
        for (int jj = 0; jj < 4; ++jj) {
            const float inv = 1.f / lrun[m][jj];
            const int q = q0 + w * 32 + m * 16 + lg * 4 + jj;
            if (q >= TOKENS) continue;
#pragma unroll
            for (int n = 0; n < 8; ++n)
                ob[(rowbase + q) * DMODEL + h * 128 + n * 16 + lr] =
                    __float2bfloat16(oacc[m][n][jj] * inv);
        }
}

// ---------------------------------------------------------------------------
// Patch-embed weight transpose (once).
// ---------------------------------------------------------------------------
__global__ __launch_bounds__(256)
void wtrans(const float* __restrict__ W, bf16* __restrict__ WT, int K, int N)
{
    __shared__ float tile[32][33];
    const int n0 = blockIdx.x * 32, k0 = blockIdx.y * 32;
    const int tx = threadIdx.x & 31, ty = threadIdx.x >> 5;
#pragma unroll
    for (int i = 0; i < 4; ++i)
        tile[ty + i * 8][tx] = W[(long)(k0 + ty + i * 8) * N + n0 + tx];
    __syncthreads();
#pragma unroll
    for (int i = 0; i < 4; ++i)
        WT[(long)(n0 + ty + i * 8) * K + k0 + tx] = __float2bfloat16(tile[tx][ty + i * 8]);
}

// ---------------------------------------------------------------------------
// Layer weight transpose. w0T AND w2T k-permuted (Phi within 64-blocks) to
// match the packed outputs of qkv-attn-chain (ob) and FFN1 (h1b).
// ---------------------------------------------------------------------------
__global__ __launch_bounds__(256)
void wtrans_layers(const float* __restrict__ Wqkv, const float* __restrict__ W0,
                   const float* __restrict__ W1, const float* __restrict__ W2,
                   bf16* __restrict__ out, int layer0)
{
    const int bb = blockIdx.x;
    const int sl = bb / 3072;
    const int l = layer0 + sl;
    int t = bb % 3072;
    bf16* base = out + (long)sl * LAYER_W;
    const float* W; bf16* WT; int K, N; int mode = 0;   // 1=qkv N perm, 2=k perm
    if (t < 768)       {            W = Wqkv + (long)l * 512 * 1536; WT = base;           K = 512;  N = 1536; mode = 1; }
    else if (t < 1024) { t -= 768;  W = W0   + (long)l * 512 * 512;  WT = base + 786432;  K = 512;  N = 512;  mode = 2; }
    else if (t < 2048) { t -= 1024; W = W1   + (long)l * 512 * 2048; WT = base + 1048576; K = 512;  N = 2048; }
    else               { t -= 2048; W = W2   + (long)l * 2048 * 512; WT = base + 2097152; K = 2048; N = 512;  mode = 2; }
    const int nx = N / 32;
    const int n0 = (t % nx) * 32, k0 = (t / nx) * 32;
    __shared__ float tile[32][33];
    const int tx = threadIdx.x & 31, ty = threadIdx.x >> 5;
#pragma unroll
    for (int i = 0; i < 4; ++i)
        tile[ty + i * 8][tx] = W[(long)(k0 + ty + i * 8) * N + n0 + tx];
    __syncthreads();
#pragma unroll
    for (int i = 0; i < 4; ++i) {
        int n = n0 + ty + i * 8;
        if (mode == 1) {
            const int d = n / 12, rr = n % 12;
            n = (rr >> 2) * 512 + (rr & 3) * 128 + d;
        }
        int kk = k0 + tx;
        if (mode == 2) {
            const int s = kk & 63;
            kk = (kk & ~63) | (((s & 15) << 2) | (s >> 4));
        }
        WT[(long)n * K + kk] = __float2bfloat16(tile[tx][ty + i * 8]);
    }
}

// ---------------------------------------------------------------------------
__global__ __launch_bounds__(64)
void patch_gather(const float* __restrict__ img, bf16* __restrict__ pat)
{
    const int bid = blockIdx.x;
    const int x  = bid % 24;
    const int p1 = (bid / 24) % 16;
    const int b  = bid / (24 * 16);
    __shared__ bf16 lds[24][48];
    const int lane = threadIdx.x;
    const int h = p1 * 24 + x;
    for (int c = 0; c < 3; ++c) {
        const float* row = img + ((long)(b * 3 + c) * 384 + h) * 384;
#pragma unroll
        for (int i = 0; i < 6; ++i) {
            const int wpix = lane + i * 64;
            const float v = row[wpix];
            const int y = wpix % 24, p2 = wpix / 24;
            lds[y][p2 * 3 + c] = __float2bfloat16(v);
        }
    }
    __syncthreads();
    for (int idx = lane; idx < 24 * 48; idx += 64) {
        const int y = idx / 48, j = idx % 48;
        pat[(long)(b * 576 + x * 24 + y) * 768 + p1 * 48 + j] = lds[y][j];
    }
}

__global__ __launch_bounds__(256)
void clsfill(const float* __restrict__ cls, const float* __restrict__ pos,
             float* __restrict__ tokf, bf16* __restrict__ xb)
{
    const int i = blockIdx.x * 256 + threadIdx.x;
    const int b = i >> 9, d = i & 511;
    const float v = cls[d] + pos[d];
    tokf[(long)b * TOKENS * DMODEL + d] = v;
    xb[(long)b * TOKENS * DMODEL + d] = __float2bfloat16(v);
}

__global__ __launch_bounds__(256)
void repack_v(const u16* __restrict__ qkv, u16* __restrict__ vhT)
{
    __shared__ u16 lds[64][136];
    const int bid = blockIdx.x;
    const int tt = bid % 10, pair = bid / 10;
    const int b = pair >> 2, h = pair & 3;
    const int tid = threadIdx.x;
    const int tl = tid >> 2, seg = tid & 3;
    const long row = (long)b * TOKENS + tt * 64 + tl;
    const u16* src = qkv + row * 1536 + 1024 + h * 128 + seg * 32;
#pragma unroll
    for (int u = 0; u < 4; ++u)
        *(uint4*)&lds[tl][seg * 32 + u * 8] = *(const uint4*)&src[u * 8];
    __syncthreads();
    const int d = tid >> 1, th = (tid & 1) * 32;
    u16* dst = vhT + ((long)pair * 128 + d) * TPAD + tt * 64 + th;
#pragma unroll
    for (int blk = 0; blk < 4; ++blk) {
        uint4 pk; u16* pp = (u16*)&pk;
#pragma unroll
        for (int j = 0; j < 8; ++j) {
            const int t = tt * 64 + th + blk * 8 + j;
            pp[j] = (t < TOKENS) ? lds[th + blk * 8 + j][d] : (u16)0;
        }
        *(uint4*)&dst[blk * 8] = pk;
    }
}

// y = LN(xin(bf16) + res(f32))*g + b -> outf, outb  (LN2)
__global__ __launch_bounds__(256)
void resln(const bf16* __restrict__ xin, const float* __restrict__ res,
           const float* __restrict__ g, const float* __restrict__ b,
           float* __restrict__ outf, bf16* __restrict__ outb, int nrows)
{
    const int row = blockIdx.x * 4 + (threadIdx.x >> 6);
    if (row >= nrows) return;
    const int lane = threadIdx.x & 63;
    const bf16* p1 = xin + (long)row * DMODEL;
    const float* p2 = res + (long)row * DMODEL;
    float v[8];
    float s = 0.f;
#pragma unroll
    for (int i = 0; i < 8; ++i) {
        v[i] = __bfloat162float(p1[lane + i * 64]) + p2[lane + i * 64];
        s += v[i];
    }
#pragma unroll
    for (int o = 32; o; o >>= 1) s += __shfl_xor(s, o);
    const float mean = s * (1.f / 512.f);
    float q = 0.f;
#pragma unroll
    for (int i = 0; i < 8; ++i) { const float d = v[i] - mean; q += d * d; }
#pragma unroll
    for (int o = 32; o; o >>= 1) q += __shfl_xor(q, o);
    const float rs = rsqrtf(q * (1.f / 512.f) + 1e-5f);
#pragma unroll
    for (int i = 0; i < 8; ++i) {
        const int c = lane + i * 64;
        const float o = (v[i] - mean) * rs * g[c] + b[c];
        outf[(long)row * DMODEL + c] = o;
        outb[(long)row * DMODEL + c] = __float2bfloat16(o);
    }
}

__global__ __launch_bounds__(64)
void head_k(const float* __restrict__ tokf, const float* __restrict__ Wh,
            const float* __restrict__ bh, float* __restrict__ out)
{
    const int b = blockIdx.x;
    const int lane = threadIdx.x;
    const float* x = tokf + (long)b * TOKENS * DMODEL;
    float acc[10] = {};
#pragma unroll
    for (int i = 0; i < 8; ++i) {
        const int d = lane + i * 64;
        const float xv = x[d];
        const float* wr = Wh + (long)d * 10;
#pragma unroll
        for (int c = 0; c < 10; ++c) acc[c] += xv * wr[c];
    }
#pragma unroll
    for (int c = 0; c < 10; ++c)
#pragma unroll
        for (int o = 32; o; o >>= 1) acc[c] += __shfl_xor(acc[c], o);
    if (lane == 0) {
#pragma unroll
        for (int c = 0; c < 10; ++c) out[b * 10 + c] = acc[c] + bh[c];
    }
}

// ---------------------------------------------------------------------------
extern "C" void kernel_launch(void* const* d_in, const int* in_sizes, int n_in,
                              void* d_out, int out_size, void* d_ws, size_t ws_size,
                              hipStream_t stream)
{
    (void)in_sizes; (void)n_in; (void)out_size;
    const float* img    = (const float*)d_in[0];
    const float* Wpatch = (const float*)d_in[1];
    const float* bpatch = (const float*)d_in[2];
    const float* clstk  = (const float*)d_in[3];
    const float* pos    = (const float*)d_in[4];
    const float* Wqkv   = (const float*)d_in[5];
    const float* W0     = (const float*)d_in[6];
    const float* g1     = (const float*)d_in[7];
    const float* b1     = (const float*)d_in[8];
    const float* g2     = (const float*)d_in[9];
    const float* b2     = (const float*)d_in[10];
    const float* W1     = (const float*)d_in[11];
    const float* bb1    = (const float*)d_in[12];
    const float* W2     = (const float*)d_in[13];
    const float* bb2    = (const float*)d_in[14];
    const float* Whead  = (const float*)d_in[15];
    const float* bhead  = (const float*)d_in[16];

    // ---- config ladder: (batch chunk, weight buffers) ----
    static const int cand[7][2] = {{32,6},{32,1},{16,1},{8,1},{4,1},{2,1},{1,1}};
    int Bc = 0, nW = 1;
    size_t o_tokf=0, o_xb=0, o_R1=0, o_R2=0, o_ob=0, o_wp=0, o_wr=0;
    for (int ci = 0; ci < 7; ++ci) {
        const int bc = cand[ci][0], nw = cand[ci][1];
        const long Mrows = (long)bc * TOKENS;
        const long Mpad  = ((Mrows + 127) / 128) * 128;
        size_t off = 0;
        auto take = [&](size_t sz) { size_t o = off; off += (sz + 255) & ~(size_t)255; return o; };
        size_t t_tokf = take((size_t)Mpad * 512 * 4);
        size_t t_xb   = take((size_t)Mpad * 512 * 2);
        size_t t_R1   = take((size_t)Mpad * 2048 * 2);          // pat | qkv | h1b
        size_t r2a = (size_t)bc * 4 * TPAD * 128 * 2;           // vhT
        size_t r2b = (size_t)Mpad * 512 * 2;                    // t1b (bf16)
        size_t t_R2 = take(r2a > r2b ? r2a : r2b);
        size_t t_ob   = take((size_t)Mpad * 512 * 2);
        size_t t_wp   = take((size_t)512 * 768 * 2);
        size_t t_wr   = take((size_t)nw * LAYER_W * 2);
        if (off <= ws_size) {
            Bc = bc; nW = nw;
            o_tokf=t_tokf; o_xb=t_xb; o_R1=t_R1; o_R2=t_R2; o_ob=t_ob; o_wp=t_wp; o_wr=t_wr;
            break;
        }
    }
    if (Bc == 0) return;

    const long Mrows = (long)Bc * TOKENS;
    const long Mpad  = ((Mrows + 127) / 128) * 128;
    const int  NP    = Bc * 4;
    const int  gy128 = (int)(Mpad / 128);
    const int  nproj = (int)((Mrows + 63) / 64);
    const int  gyp   = (int)(((long)Bc * 576 + 127) / 128);

    char* base = (char*)d_ws;
    float* tokf = (float*)(base + o_tokf);
    bf16*  xb   = (bf16*)(base + o_xb);
    char*  R1   = base + o_R1;
    char*  R2   = base + o_R2;
    bf16*  ob   = (bf16*)(base + o_ob);
    bf16*  wpT  = (bf16*)(base + o_wp);
    bf16*  wAll = (bf16*)(base + o_wr);

    u16*  qkvb = (u16*)R1;
    bf16* pat  = (bf16*)R1;
    u16*  h1b  = (u16*)R1;
    u16*  vhT  = (u16*)R2;
    bf16* t1b  = (bf16*)R2;

    wtrans<<<dim3(512 / 32, 768 / 32), 256, 0, stream>>>(Wpatch, wpT, 768, 512);
    if (nW == 6)
        wtrans_layers<<<6 * 3072, 256, 0, stream>>>(Wqkv, W0, W1, W2, wAll, 0);

    const int nchunks = 32 / Bc;
    for (int ch = 0; ch < nchunks; ++ch) {
        const float* img_c = img + (long)ch * Bc * 3 * 384 * 384;

        hipMemsetAsync(xb, 0, (size_t)Mpad * 512 * 2, stream);   // pad rows -> exact 0
        clsfill<<<Bc * 2, 256, 0, stream>>>(clstk, pos, tokf, xb);
        patch_gather<<<Bc * 16 * 24, 64, 0, stream>>>(img_c, pat);
        gemm_bt32<false, 3><<<dim3(4, gyp), 256, 0, stream>>>(
            (const u16*)pat, 768, (const u16*)wpT, 768,
            xb, tokf, 512, bpatch, pos, 768, Bc * 576);

        for (int l = 0; l < 6; ++l) {
            const bf16* wL = wAll + (nW == 6 ? (long)l * LAYER_W : 0);
            if (nW == 1)
                wtrans_layers<<<3072, 256, 0, stream>>>(Wqkv, W0, W1, W2, wAll, l);
            const u16* wqkvT = (const u16*)wL;
            const u16* w0T   = (const u16*)(wL + 786432);
            const u16* w1T   = (const u16*)(wL + 1048576);
            const u16* w2T   = (const u16*)(wL + 2097152);

            // qkv = x @ Wqkv  (PACKED interleaved stores; Q/K pairing invariant,
            // V's perm compensated by w0T k-perm downstream)
            gemm_bt32<false, 1><<<dim3(12, gy128), 256, 0, stream>>>(
                (const u16*)xb, 512, wqkvT, 512,
                (bf16*)qkvb, nullptr, 1536, nullptr, nullptr, 512, (int)Mpad);

            repack_v<<<NP * 10, 256, 0, stream>>>(qkvb, vhT);
            attn_flash<<<dim3(5, NP), 256, 0, stream>>>(qkvb, vhT, ob);

            // fused proj + residual + LN1 -> tokf, xb  (w0T k-permuted)
            proj_ln<<<nproj, 512, 0, stream>>>(
                (const u16*)ob, w0T, tokf, g1 + l * 512, b1 + l * 512,
                tokf, xb, (int)Mrows);

            // h1 = gelu(y @ W1 + bb1), packed interleaved stores
            gemm_bt32<true, 1><<<dim3(16, gy128), 256, 0, stream>>>(
                (const u16*)xb, 512, w1T, 512,
                (bf16*)h1b, nullptr, 2048, bb1 + l * 2048, nullptr, 512, (int)Mrows);

            // t1 = h1 @ W2 + bb2  (w2T k-permuted; bf16 out)
            gemm_bt32<false, 0><<<dim3(4, gy128), 256, 0, stream>>>(
                (const u16*)h1b, 2048, w2T, 2048,
                t1b, nullptr, 512, bb2 + l * 512, nullptr, 2048, (int)Mrows);

            // x = LN(t1 + y) -> tokf, xb
            resln<<<(int)((Mrows + 3) / 4), 256, 0, stream>>>(
                t1b, tokf, g2 + l * 512, b2 + l * 512, tokf, xb, (int)Mrows);
        }

        head_k<<<Bc, 64, 0, stream>>>(tokf, Whead, bhead, (float*)d_out + (long)ch * Bc * 10);
    }
}